// Round 10
// baseline (3077.753 us; speedup 1.0000x reference)
//
#include <hip/hip_runtime.h>
#include <cstdint>
#include <cstddef>

// ---------------------------------------------------------------------------
// EncodeProcessDecode GNN, fp32.
// R10: LDS-pipe thinning in the tiled kernels. R9 profile: edge core flat at
// ~614us, VALUBusy 59% — LDS pipe (~12.5k cyc/wave: scalar b32 A/H reads)
// co-saturated with VALU (12.3k FMA cyc). Now: A/H strides 65->68 (16B
// aligned) so GEMM1 A-reads are 1 ds_read_b128 per 4k per edge and GEMM2
// H-reads are 1 b128 per k (both bank-verified 2-way/broadcast = free);
// H-writes become 4-way (1.58x, 32 writes only). GEMM2 W staged in 2x64-row
// phases (4 fewer barriers). LDS 52-53KB -> still 3 blocks/CU.
// Kept: CSR-permuted edge state, fp64 order-invariant agg, W reg-prefetch,
// plan tiers by ws_size.
// ---------------------------------------------------------------------------

__device__ __forceinline__ float f4c(const float4& v, int k) {
    return k == 0 ? v.x : (k == 1 ? v.y : (k == 2 ? v.z : v.w));
}

__global__ void k_zero(int* __restrict__ p, int n) {
    int i = blockIdx.x * 256 + threadIdx.x;
    if (i < n) p[i] = 0;
}

// ---------------- CSR build ----------------

__global__ void k_hist(const int* __restrict__ dst, int* __restrict__ counts, int E) {
    int e = blockIdx.x * 256 + threadIdx.x;
    if (e < E) atomicAdd(&counts[dst[e]], 1);
}

__global__ __launch_bounds__(1024) void k_scan(
    const int* __restrict__ counts, int* __restrict__ row_off,
    int* __restrict__ cursor, float* __restrict__ inv_cnt, int N) {
    __shared__ int wsum[16];
    int t = threadIdx.x;
    int wave = t >> 6, lane = t & 63;
    int carry = 0;
    for (int base = 0; base < N; base += 1024) {
        int i = base + t;
        int v = (i < N) ? counts[i] : 0;
        int s = v;
        #pragma unroll
        for (int off = 1; off < 64; off <<= 1) {
            int u = __shfl_up(s, off, 64);
            if (lane >= off) s += u;
        }
        if (lane == 63) wsum[wave] = s;
        __syncthreads();
        int wpre = 0, full = 0;
        #pragma unroll
        for (int wv = 0; wv < 16; wv++) {
            int x = wsum[wv];
            full += x;
            if (wv < wave) wpre += x;
        }
        if (i < N) {
            int excl = carry + wpre + s - v;
            row_off[i] = excl;
            cursor[i]  = excl;
            inv_cnt[i] = 1.0f / (float)((v > 0) ? v : 1);
        }
        carry += full;
        __syncthreads();
    }
    if (t == 0) row_off[N] = carry;
}

__global__ void k_fill(const int* __restrict__ dst, int* __restrict__ cursor,
                       int* __restrict__ edge_list, int E) {
    int e = blockIdx.x * 256 + threadIdx.x;
    if (e < E) {
        int pos = atomicAdd(&cursor[dst[e]], 1);
        edge_list[pos] = e;
    }
}

__global__ void k_perm_idx(const int* __restrict__ elist,
                           const int* __restrict__ src, const int* __restrict__ dst,
                           int* __restrict__ src_p, int* __restrict__ dst_p, int E) {
    int i = blockIdx.x * 256 + threadIdx.x;
    if (i < E) {
        int e = elist[i];
        src_p[i] = src[e];
        dst_p[i] = dst[e];
    }
}

// ---------------- encoder helper table ----------------

__global__ void k_embW(const float* __restrict__ emb, const float* __restrict__ W0,
                       const float* __restrict__ b0, float* __restrict__ embW) {
    int c = threadIdx.x;  // 128 threads
    #pragma unroll
    for (int p = 0; p < 2; p++) {
        float acc = b0[c];
        #pragma unroll
        for (int k = 0; k < 16; k++)
            acc = fmaf(emb[p * 16 + k], W0[(31 + k) * 128 + c], acc);
        embW[p * 128 + c] = acc;
    }
}

// ---------------- thread-per-row building blocks ----------------

__device__ __forceinline__ void g1_accum32(
    const float4* __restrict__ a4, int kk4,
    const float* __restrict__ W, int cbase, float* __restrict__ h) {
    #pragma clang loop unroll(disable)
    for (int kk = 0; kk < kk4; kk++) {
        float4 a = a4[kk];
        const float* wr = W + (size_t)kk * 4 * 128 + cbase;
        const float4* w0 = reinterpret_cast<const float4*>(wr);
        const float4* w1 = reinterpret_cast<const float4*>(wr + 128);
        const float4* w2 = reinterpret_cast<const float4*>(wr + 256);
        const float4* w3 = reinterpret_cast<const float4*>(wr + 384);
        #pragma unroll
        for (int cg = 0; cg < 8; cg++) {
            float4 p = w0[cg], q = w1[cg], r = w2[cg], s = w3[cg];
            h[cg*4+0] = fmaf(a.w, s.x, fmaf(a.z, r.x, fmaf(a.y, q.x, fmaf(a.x, p.x, h[cg*4+0]))));
            h[cg*4+1] = fmaf(a.w, s.y, fmaf(a.z, r.y, fmaf(a.y, q.y, fmaf(a.x, p.y, h[cg*4+1]))));
            h[cg*4+2] = fmaf(a.w, s.z, fmaf(a.z, r.z, fmaf(a.y, q.z, fmaf(a.x, p.z, h[cg*4+2]))));
            h[cg*4+3] = fmaf(a.w, s.w, fmaf(a.z, r.w, fmaf(a.y, q.w, fmaf(a.x, p.w, h[cg*4+3]))));
        }
    }
}

__device__ __forceinline__ void g1_tail3(
    float x, float y, float z, const float* __restrict__ W, int cbase,
    float* __restrict__ h) {
    const float4* w0 = reinterpret_cast<const float4*>(W + cbase);
    const float4* w1 = reinterpret_cast<const float4*>(W + 128 + cbase);
    const float4* w2 = reinterpret_cast<const float4*>(W + 256 + cbase);
    #pragma unroll
    for (int cg = 0; cg < 8; cg++) {
        float4 p = w0[cg], q = w1[cg], r = w2[cg];
        h[cg*4+0] = fmaf(z, r.x, fmaf(y, q.x, fmaf(x, p.x, h[cg*4+0])));
        h[cg*4+1] = fmaf(z, r.y, fmaf(y, q.y, fmaf(x, p.y, h[cg*4+1])));
        h[cg*4+2] = fmaf(z, r.z, fmaf(y, q.z, fmaf(x, p.z, h[cg*4+2])));
        h[cg*4+3] = fmaf(z, r.w, fmaf(y, q.w, fmaf(x, p.w, h[cg*4+3])));
    }
}

__device__ __forceinline__ void g2_accum64(
    float* __restrict__ sb, const float* __restrict__ hc,
    const float* __restrict__ W1, int kbase, int rs, float* __restrict__ o) {
    int t = threadIdx.x;
    #pragma unroll
    for (int k = 0; k < 32; k++) sb[k * 256 + t] = hc[k];
    __syncthreads();
    #pragma clang loop unroll(disable)
    for (int k = 0; k < 32; k++) {
        float hk = sb[k * 256 + t];
        const float4* w = reinterpret_cast<const float4*>(W1 + (size_t)(kbase + k) * rs);
        #pragma unroll
        for (int cg = 0; cg < 16; cg++) {
            float4 wv = w[cg];
            o[cg*4+0] = fmaf(hk, wv.x, o[cg*4+0]);
            o[cg*4+1] = fmaf(hk, wv.y, o[cg*4+1]);
            o[cg*4+2] = fmaf(hk, wv.z, o[cg*4+2]);
            o[cg*4+3] = fmaf(hk, wv.w, o[cg*4+3]);
        }
    }
    __syncthreads();
}

// ---------------- node encoder (tail only) — R5 version ---------------------

__global__ __launch_bounds__(256, 2) void k_enc_node_tail(
    const float* __restrict__ nodeF, const float* __restrict__ embW,
    const float* __restrict__ W0, const float* __restrict__ W1,
    const float* __restrict__ b1, float* __restrict__ nodeT, int N) {
    __shared__ float sb[32 * 256];
    int n = blockIdx.x * 256 + threadIdx.x;
    bool valid = n < N;
    int nc = valid ? n : N - 1;
    const float4* nf4 = reinterpret_cast<const float4*>(nodeF + (size_t)nc * 32);
    float4 v7 = nf4[7];
    int p = (int)(v7.w + 0.5f);
    const float4* ew = reinterpret_cast<const float4*>(embW + p * 128);

    float o[64];
    const float4* bv = reinterpret_cast<const float4*>(b1 + 64);
    #pragma unroll
    for (int i = 0; i < 16; i++) {
        float4 b = bv[i];
        o[4*i+0] = b.x; o[4*i+1] = b.y; o[4*i+2] = b.z; o[4*i+3] = b.w;
    }
    #pragma unroll
    for (int ch = 0; ch < 4; ch++) {
        int cbase = ch * 32;
        float h[32];
        #pragma unroll
        for (int i = 0; i < 8; i++) {
            float4 u = ew[ch*8 + i];
            h[4*i+0] = u.x; h[4*i+1] = u.y; h[4*i+2] = u.z; h[4*i+3] = u.w;
        }
        g1_accum32(nf4, 7, W0, cbase, h);
        g1_tail3(v7.x, v7.y, v7.z, W0 + 28*128, cbase, h);
        #pragma unroll
        for (int i = 0; i < 32; i++) h[i] = fmaxf(h[i], 0.0f);
        g2_accum64(sb, h, W1 + 64, cbase, 128, o);
    }
    if (valid) {
        float4* out4 = reinterpret_cast<float4*>(nodeT + (size_t)n * 64);
        #pragma unroll
        for (int i = 0; i < 16; i++)
            out4[i] = make_float4(o[4*i], o[4*i+1], o[4*i+2], o[4*i+3]);
    }
}

// ---------------- tiled edge encoder (R10: b128 H-reads, 2-phase W1) --------

__global__ __launch_bounds__(256, 3) void k_enc_edge_T(
    const float* __restrict__ edgeF, const int* __restrict__ perm, int usePerm,
    const float* __restrict__ W0, const float* __restrict__ b0,
    const float* __restrict__ W1, const float* __restrict__ b1,
    float* __restrict__ edgeT, int E) {
    __shared__ float H[128 * 68];     // H[c][e], stride 68
    __shared__ float Wbuf[64 * 68];   // W1 chunk [64][68]
    __shared__ float Xs[64 * 4];

    int t = threadIdx.x;
    int base = blockIdx.x * 64;

    if (t < 192) {
        int i = t / 3, j = t - i * 3;
        int e = base + i; int ec = (e < E) ? e : E - 1;
        int e2 = usePerm ? perm[ec] : ec;
        Xs[i * 4 + j] = edgeF[(size_t)e2 * 3 + j];
    }
    __syncthreads();

    int eg = t & 15, cg = t >> 4;
    float c1[4][8];
    {
        float4 b0a = *reinterpret_cast<const float4*>(b0 + cg * 8);
        float4 b0b = *reinterpret_cast<const float4*>(b0 + cg * 8 + 4);
        float bb[8] = {b0a.x,b0a.y,b0a.z,b0a.w,b0b.x,b0b.y,b0b.z,b0b.w};
        #pragma unroll
        for (int ie = 0; ie < 4; ie++)
            #pragma unroll
            for (int jc = 0; jc < 8; jc++) c1[ie][jc] = bb[jc];
    }
    #pragma unroll
    for (int k = 0; k < 3; k++) {
        float4 wa = *reinterpret_cast<const float4*>(W0 + k * 128 + cg * 8);
        float4 wb = *reinterpret_cast<const float4*>(W0 + k * 128 + cg * 8 + 4);
        float ww[8] = {wa.x,wa.y,wa.z,wa.w,wb.x,wb.y,wb.z,wb.w};
        #pragma unroll
        for (int ie = 0; ie < 4; ie++) {
            float a = Xs[(eg + 16 * ie) * 4 + k];
            #pragma unroll
            for (int jc = 0; jc < 8; jc++)
                c1[ie][jc] = fmaf(a, ww[jc], c1[ie][jc]);
        }
    }

    // prefetch W1 phase-0 (rows 0..63, cols 64..128)
    int r2 = t >> 2, cb2 = t & 3;
    float4 wreg2[4];
    {
        const float4* wr = reinterpret_cast<const float4*>(
            W1 + (size_t)r2 * 128 + 64 + cb2 * 16);
        wreg2[0]=wr[0]; wreg2[1]=wr[1]; wreg2[2]=wr[2]; wreg2[3]=wr[3];
    }

    #pragma unroll
    for (int ie = 0; ie < 4; ie++)
        #pragma unroll
        for (int jc = 0; jc < 8; jc++)
            H[(cg * 8 + jc) * 68 + eg + 16 * ie] = fmaxf(c1[ie][jc], 0.0f);

    int eg2 = t & 15, cg2 = t >> 4;
    float c2[4][4];
    {
        float4 bv = *reinterpret_cast<const float4*>(b1 + 64 + cg2 * 4);
        #pragma unroll
        for (int ie = 0; ie < 4; ie++) {
            c2[ie][0]=bv.x; c2[ie][1]=bv.y; c2[ie][2]=bv.z; c2[ie][3]=bv.w;
        }
    }
    #pragma clang loop unroll(disable)
    for (int phase = 0; phase < 2; phase++) {
        __syncthreads();                  // H written / prev Wbuf reads done
        {
            float4* wd = reinterpret_cast<float4*>(Wbuf + r2 * 68 + cb2 * 16);
            wd[0]=wreg2[0]; wd[1]=wreg2[1]; wd[2]=wreg2[2]; wd[3]=wreg2[3];
        }
        __syncthreads();
        if (phase < 1) {
            const float4* wr = reinterpret_cast<const float4*>(
                W1 + (size_t)(64 + r2) * 128 + 64 + cb2 * 16);
            wreg2[0]=wr[0]; wreg2[1]=wr[1]; wreg2[2]=wr[2]; wreg2[3]=wr[3];
        }
        #pragma clang loop unroll_count(4)
        for (int k = 0; k < 64; k++) {
            int c = phase * 64 + k;
            float4 av = *reinterpret_cast<const float4*>(H + c * 68 + eg2 * 4);
            float4 b4 = *reinterpret_cast<const float4*>(Wbuf + k * 68 + cg2 * 4);
            float bb[4] = {b4.x, b4.y, b4.z, b4.w};
            float aa[4] = {av.x, av.y, av.z, av.w};
            #pragma unroll
            for (int jc = 0; jc < 4; jc++) {
                c2[0][jc] = fmaf(aa[0], bb[jc], c2[0][jc]);
                c2[1][jc] = fmaf(aa[1], bb[jc], c2[1][jc]);
                c2[2][jc] = fmaf(aa[2], bb[jc], c2[2][jc]);
                c2[3][jc] = fmaf(aa[3], bb[jc], c2[3][jc]);
            }
        }
    }
    #pragma unroll
    for (int ie = 0; ie < 4; ie++) {
        int e = base + eg2 * 4 + ie;
        if (e < E) {
            *reinterpret_cast<float4*>(edgeT + (size_t)e * 64 + cg2 * 4) =
                make_float4(c2[ie][0], c2[ie][1], c2[ie][2], c2[ie][3]);
        }
    }
}

// ------------- per-step node projection (Pd only) — R5 version --------------

__global__ __launch_bounds__(256, 4) void k_node_pre_d(
    const float* __restrict__ nodeT, const float* __restrict__ W0,
    const float* __restrict__ b0, float* __restrict__ Pd, int N) {
    int n = blockIdx.x * 256 + threadIdx.x;
    bool valid = n < N;
    int nc = valid ? n : N - 1;
    const float4* a4 = reinterpret_cast<const float4*>(nodeT + (size_t)nc * 64);

    #pragma unroll
    for (int ch = 0; ch < 4; ch++) {
        int cbase = ch * 32;
        float h[32];
        const float4* b0v = reinterpret_cast<const float4*>(b0 + cbase);
        #pragma unroll
        for (int i = 0; i < 8; i++) {
            float4 b = b0v[i];
            h[4*i+0] = b.x; h[4*i+1] = b.y; h[4*i+2] = b.z; h[4*i+3] = b.w;
        }
        g1_accum32(a4, 16, W0 + 64*128, cbase, h);
        if (valid) {
            float4* o4 = reinterpret_cast<float4*>(Pd + (size_t)n * 128 + cbase);
            #pragma unroll
            for (int i = 0; i < 8; i++)
                o4[i] = make_float4(h[4*i], h[4*i+1], h[4*i+2], h[4*i+3]);
        }
    }
}

// ------------- tiled edge core (R10: b128 A/H reads, 2-phase GEMM2 W) -------

__global__ __launch_bounds__(256, 3) void k_edge_core_T(
    float* __restrict__ edgeT, const float* __restrict__ Pd,
    const float* __restrict__ nodeT,
    const int* __restrict__ srcI, const int* __restrict__ dstI,
    const float* __restrict__ W0, const float* __restrict__ W1,
    const float* __restrict__ b1, int E) {
    __shared__ float Abuf[2 * 64 * 68];   // A_e | A_s (stride 68); later H[128][68]
    __shared__ float Wbuf[64 * 68];       // GEMM1: [32][132]; GEMM2: [64][68]

    int t = threadIdx.x;
    int base = blockIdx.x * 64;

    // ---- stage A_e (edgeT rows) and A_s (nodeT[src] rows), float4 ----
    {
        int i = t >> 2, q = t & 3;
        int e = base + i; int ec = (e < E) ? e : E - 1;
        const float4* er = reinterpret_cast<const float4*>(edgeT + (size_t)ec * 64 + q * 16);
        int s = srcI[ec];
        const float4* sr = reinterpret_cast<const float4*>(nodeT + (size_t)s * 64 + q * 16);
        float4* ae = reinterpret_cast<float4*>(Abuf + i * 68 + q * 16);
        float4* as = reinterpret_cast<float4*>(Abuf + 64 * 68 + i * 68 + q * 16);
        #pragma unroll
        for (int j4 = 0; j4 < 4; j4++) { ae[j4] = er[j4]; as[j4] = sr[j4]; }
    }

    // ---- init C1 from Pd[dst]; edges e = eg + 16*ie ----
    int eg = t & 15, cg = t >> 4;
    float c1[4][8];
    #pragma unroll
    for (int ie = 0; ie < 4; ie++) {
        int e = base + eg + 16 * ie; int ec = (e < E) ? e : E - 1;
        int d = dstI[ec];
        const float4* pr = reinterpret_cast<const float4*>(Pd + (size_t)d * 128 + cg * 8);
        float4 p0 = pr[0], p1 = pr[1];
        c1[ie][0]=p0.x; c1[ie][1]=p0.y; c1[ie][2]=p0.z; c1[ie][3]=p0.w;
        c1[ie][4]=p1.x; c1[ie][5]=p1.y; c1[ie][6]=p1.z; c1[ie][7]=p1.w;
    }

    // ---- GEMM1: 4 phases, W rows {0,32,128,160}, reg-prefetched ----
    int wr_r = t >> 3, wr_cb = t & 7;
    float4 wreg[4];
    {
        const float4* wr = reinterpret_cast<const float4*>(
            W0 + (size_t)wr_r * 128 + wr_cb * 16);
        wreg[0]=wr[0]; wreg[1]=wr[1]; wreg[2]=wr[2]; wreg[3]=wr[3];
    }
    #pragma clang loop unroll(disable)
    for (int phase = 0; phase < 4; phase++) {
        const float* Asrc = Abuf + ((phase < 2) ? 0 : 64 * 68);
        int koff = (phase & 1) * 32;
        __syncthreads();                  // A staged (p0) / prev Wbuf reads done
        {
            float4* wd = reinterpret_cast<float4*>(Wbuf + wr_r * 132 + wr_cb * 16);
            wd[0]=wreg[0]; wd[1]=wreg[1]; wd[2]=wreg[2]; wd[3]=wreg[3];
        }
        __syncthreads();
        if (phase < 3) {
            int wrow_n = (phase + 1 < 2) ? (phase + 1) * 32 : 128 + (phase - 1) * 32;
            const float4* wr = reinterpret_cast<const float4*>(
                W0 + (size_t)(wrow_n + wr_r) * 128 + wr_cb * 16);
            wreg[0]=wr[0]; wreg[1]=wr[1]; wreg[2]=wr[2]; wreg[3]=wr[3];
        }
        #pragma clang loop unroll_count(2)
        for (int k4 = 0; k4 < 8; k4++) {
            float4 av[4];
            #pragma unroll
            for (int ie = 0; ie < 4; ie++)
                av[ie] = *reinterpret_cast<const float4*>(
                    Asrc + (eg + 16 * ie) * 68 + koff + k4 * 4);
            #pragma unroll
            for (int kk = 0; kk < 4; kk++) {
                const float* wrp = Wbuf + (k4 * 4 + kk) * 132 + cg * 8;
                float4 bq0 = *reinterpret_cast<const float4*>(wrp);
                float4 bq1 = *reinterpret_cast<const float4*>(wrp + 4);
                float bb[8] = {bq0.x,bq0.y,bq0.z,bq0.w,bq1.x,bq1.y,bq1.z,bq1.w};
                float a0 = f4c(av[0], kk), a1 = f4c(av[1], kk);
                float a2 = f4c(av[2], kk), a3 = f4c(av[3], kk);
                #pragma unroll
                for (int jc = 0; jc < 8; jc++) {
                    c1[0][jc] = fmaf(a0, bb[jc], c1[0][jc]);
                    c1[1][jc] = fmaf(a1, bb[jc], c1[1][jc]);
                    c1[2][jc] = fmaf(a2, bb[jc], c1[2][jc]);
                    c1[3][jc] = fmaf(a3, bb[jc], c1[3][jc]);
                }
            }
        }
    }

    // prefetch W1 phase-0 (rows 0..63 of [128][64])
    int r2 = t >> 2, cb2 = t & 3;
    float4 wreg2[4];
    {
        const float4* wr = reinterpret_cast<const float4*>(
            W1 + (size_t)r2 * 64 + cb2 * 16);
        wreg2[0]=wr[0]; wreg2[1]=wr[1]; wreg2[2]=wr[2]; wreg2[3]=wr[3];
    }

    __syncthreads();                      // all A reads done -> alias as H
    float* H = Abuf;                      // H[c][e], stride 68
    #pragma unroll
    for (int ie = 0; ie < 4; ie++)
        #pragma unroll
        for (int jc = 0; jc < 8; jc++)
            H[(cg*8 + jc) * 68 + eg + 16*ie] = fmaxf(c1[ie][jc], 0.0f);

    // ---- GEMM2: 2 phases of 64 W1 rows ----
    int eg2 = t & 15, cg2 = t >> 4;
    float c2[4][4];
    {
        float4 bv = *reinterpret_cast<const float4*>(b1 + cg2 * 4);
        #pragma unroll
        for (int ie = 0; ie < 4; ie++) {
            c2[ie][0]=bv.x; c2[ie][1]=bv.y; c2[ie][2]=bv.z; c2[ie][3]=bv.w;
        }
    }
    #pragma clang loop unroll(disable)
    for (int phase = 0; phase < 2; phase++) {
        __syncthreads();                  // H written (p0) / prev Wbuf reads done
        {
            float4* wd = reinterpret_cast<float4*>(Wbuf + r2 * 68 + cb2 * 16);
            wd[0]=wreg2[0]; wd[1]=wreg2[1]; wd[2]=wreg2[2]; wd[3]=wreg2[3];
        }
        __syncthreads();
        if (phase < 1) {
            const float4* wr = reinterpret_cast<const float4*>(
                W1 + (size_t)(64 + r2) * 64 + cb2 * 16);
            wreg2[0]=wr[0]; wreg2[1]=wr[1]; wreg2[2]=wr[2]; wreg2[3]=wr[3];
        }
        #pragma clang loop unroll_count(4)
        for (int k = 0; k < 64; k++) {
            int c = phase * 64 + k;
            float4 av = *reinterpret_cast<const float4*>(H + c * 68 + eg2 * 4);
            float4 b4 = *reinterpret_cast<const float4*>(Wbuf + k * 68 + cg2 * 4);
            float bb[4] = {b4.x, b4.y, b4.z, b4.w};
            float aa[4] = {av.x, av.y, av.z, av.w};
            #pragma unroll
            for (int jc = 0; jc < 4; jc++) {
                c2[0][jc] = fmaf(aa[0], bb[jc], c2[0][jc]);
                c2[1][jc] = fmaf(aa[1], bb[jc], c2[1][jc]);
                c2[2][jc] = fmaf(aa[2], bb[jc], c2[2][jc]);
                c2[3][jc] = fmaf(aa[3], bb[jc], c2[3][jc]);
            }
        }
    }

    #pragma unroll
    for (int ie = 0; ie < 4; ie++) {
        int e = base + eg2 * 4 + ie;
        if (e < E) {
            float4* er = reinterpret_cast<float4*>(edgeT + (size_t)e * 64 + cg2 * 4);
            float4 old = *er;
            old.x += c2[ie][0]; old.y += c2[ie][1];
            old.z += c2[ie][2]; old.w += c2[ie][3];
            *er = old;
        }
    }
}

// ------------- tiled node core (R10: b128 A/H reads, 2-phase GEMM2 W) -------

__global__ __launch_bounds__(256, 3) void k_node_core_T(
    const float* __restrict__ aggT, float* __restrict__ nodeT,
    const float* __restrict__ W0, const float* __restrict__ b0,
    const float* __restrict__ W1, const float* __restrict__ b1, int N) {
    __shared__ float Abuf[64 * 136];      // A[n][k] stride 132 (8448 used); H[128][68] (8704)
    __shared__ float Wbuf[64 * 68];

    int t = threadIdx.x;
    int base = blockIdx.x * 64;

    // ---- stage A: cols 0..63 = aggT row, 64..127 = nodeT row ----
    {
        int i = t >> 2, q = t & 3;
        int n = base + i; int nc = (n < N) ? n : N - 1;
        const float4* gr = reinterpret_cast<const float4*>(aggT + (size_t)nc * 64 + q * 16);
        const float4* tr = reinterpret_cast<const float4*>(nodeT + (size_t)nc * 64 + q * 16);
        float4* ag = reinterpret_cast<float4*>(Abuf + i * 132 + q * 16);
        float4* at = reinterpret_cast<float4*>(Abuf + i * 132 + 64 + q * 16);
        #pragma unroll
        for (int j4 = 0; j4 < 4; j4++) { ag[j4] = gr[j4]; at[j4] = tr[j4]; }
    }

    int ng = t & 15, cg = t >> 4;
    float c1[4][8];
    {
        float4 b0a = *reinterpret_cast<const float4*>(b0 + cg * 8);
        float4 b0b = *reinterpret_cast<const float4*>(b0 + cg * 8 + 4);
        float bb[8] = {b0a.x,b0a.y,b0a.z,b0a.w,b0b.x,b0b.y,b0b.z,b0b.w};
        #pragma unroll
        for (int in = 0; in < 4; in++)
            #pragma unroll
            for (int jc = 0; jc < 8; jc++) c1[in][jc] = bb[jc];
    }

    int wr_r = t >> 3, wr_cb = t & 7;
    float4 wreg[4];
    {
        const float4* wr = reinterpret_cast<const float4*>(
            W0 + (size_t)wr_r * 128 + wr_cb * 16);
        wreg[0]=wr[0]; wreg[1]=wr[1]; wreg[2]=wr[2]; wreg[3]=wr[3];
    }
    #pragma clang loop unroll(disable)
    for (int phase = 0; phase < 4; phase++) {
        int koff = phase * 32;
        __syncthreads();
        {
            float4* wd = reinterpret_cast<float4*>(Wbuf + wr_r * 132 + wr_cb * 16);
            wd[0]=wreg[0]; wd[1]=wreg[1]; wd[2]=wreg[2]; wd[3]=wreg[3];
        }
        __syncthreads();
        if (phase < 3) {
            const float4* wr = reinterpret_cast<const float4*>(
                W0 + (size_t)((phase + 1) * 32 + wr_r) * 128 + wr_cb * 16);
            wreg[0]=wr[0]; wreg[1]=wr[1]; wreg[2]=wr[2]; wreg[3]=wr[3];
        }
        #pragma clang loop unroll_count(2)
        for (int k4 = 0; k4 < 8; k4++) {
            float4 av[4];
            #pragma unroll
            for (int in = 0; in < 4; in++)
                av[in] = *reinterpret_cast<const float4*>(
                    Abuf + (ng + 16 * in) * 132 + koff + k4 * 4);
            #pragma unroll
            for (int kk = 0; kk < 4; kk++) {
                const float* wrp = Wbuf + (k4 * 4 + kk) * 132 + cg * 8;
                float4 bq0 = *reinterpret_cast<const float4*>(wrp);
                float4 bq1 = *reinterpret_cast<const float4*>(wrp + 4);
                float bb[8] = {bq0.x,bq0.y,bq0.z,bq0.w,bq1.x,bq1.y,bq1.z,bq1.w};
                float a0 = f4c(av[0], kk), a1 = f4c(av[1], kk);
                float a2 = f4c(av[2], kk), a3 = f4c(av[3], kk);
                #pragma unroll
                for (int jc = 0; jc < 8; jc++) {
                    c1[0][jc] = fmaf(a0, bb[jc], c1[0][jc]);
                    c1[1][jc] = fmaf(a1, bb[jc], c1[1][jc]);
                    c1[2][jc] = fmaf(a2, bb[jc], c1[2][jc]);
                    c1[3][jc] = fmaf(a3, bb[jc], c1[3][jc]);
                }
            }
        }
    }

    int r2 = t >> 2, cb2 = t & 3;
    float4 wreg2[4];
    {
        const float4* wr = reinterpret_cast<const float4*>(
            W1 + (size_t)r2 * 64 + cb2 * 16);
        wreg2[0]=wr[0]; wreg2[1]=wr[1]; wreg2[2]=wr[2]; wreg2[3]=wr[3];
    }

    __syncthreads();
    float* H = Abuf;                      // H[c][n], stride 68
    #pragma unroll
    for (int in = 0; in < 4; in++)
        #pragma unroll
        for (int jc = 0; jc < 8; jc++)
            H[(cg*8 + jc) * 68 + ng + 16*in] = fmaxf(c1[in][jc], 0.0f);

    int ng2 = t & 15, cg2 = t >> 4;
    float c2[4][4];
    {
        float4 bv = *reinterpret_cast<const float4*>(b1 + cg2 * 4);
        #pragma unroll
        for (int in = 0; in < 4; in++) {
            c2[in][0]=bv.x; c2[in][1]=bv.y; c2[in][2]=bv.z; c2[in][3]=bv.w;
        }
    }
    #pragma clang loop unroll(disable)
    for (int phase = 0; phase < 2; phase++) {
        __syncthreads();
        {
            float4* wd = reinterpret_cast<float4*>(Wbuf + r2 * 68 + cb2 * 16);
            wd[0]=wreg2[0]; wd[1]=wreg2[1]; wd[2]=wreg2[2]; wd[3]=wreg2[3];
        }
        __syncthreads();
        if (phase < 1) {
            const float4* wr = reinterpret_cast<const float4*>(
                W1 + (size_t)(64 + r2) * 64 + cb2 * 16);
            wreg2[0]=wr[0]; wreg2[1]=wr[1]; wreg2[2]=wr[2]; wreg2[3]=wr[3];
        }
        #pragma clang loop unroll_count(4)
        for (int k = 0; k < 64; k++) {
            int c = phase * 64 + k;
            float4 av = *reinterpret_cast<const float4*>(H + c * 68 + ng2 * 4);
            float4 b4 = *reinterpret_cast<const float4*>(Wbuf + k * 68 + cg2 * 4);
            float bb[4] = {b4.x, b4.y, b4.z, b4.w};
            float aa[4] = {av.x, av.y, av.z, av.w};
            #pragma unroll
            for (int jc = 0; jc < 4; jc++) {
                c2[0][jc] = fmaf(aa[0], bb[jc], c2[0][jc]);
                c2[1][jc] = fmaf(aa[1], bb[jc], c2[1][jc]);
                c2[2][jc] = fmaf(aa[2], bb[jc], c2[2][jc]);
                c2[3][jc] = fmaf(aa[3], bb[jc], c2[3][jc]);
            }
        }
    }

    #pragma unroll
    for (int in = 0; in < 4; in++) {
        int n = base + ng2 * 4 + in;
        if (n < N) {
            float4* nr = reinterpret_cast<float4*>(nodeT + (size_t)n * 64 + cg2 * 4);
            float4 old = *nr;
            old.x += c2[in][0]; old.y += c2[in][1];
            old.z += c2[in][2]; old.w += c2[in][3];
            *nr = old;
        }
    }
}

// ------------- plan B edge core (all inline, original order) ----------------

__global__ __launch_bounds__(256, 2) void k_edge_core_B(
    float* __restrict__ edgeT, const float* __restrict__ nodeT,
    const int* __restrict__ src, const int* __restrict__ dst,
    const float* __restrict__ W0, const float* __restrict__ b0,
    const float* __restrict__ W1, const float* __restrict__ b1, int E) {
    __shared__ float sb[32 * 256];
    int e = blockIdx.x * 256 + threadIdx.x;
    bool valid = e < E;
    int ec = valid ? e : E - 1;
    int d = dst[ec], s = src[ec];
    const float4* a4 = reinterpret_cast<const float4*>(edgeT + (size_t)ec * 64);
    const float4* d4 = reinterpret_cast<const float4*>(nodeT + (size_t)d * 64);
    const float4* s4 = reinterpret_cast<const float4*>(nodeT + (size_t)s * 64);

    float o[64];
    const float4* bv = reinterpret_cast<const float4*>(b1);
    #pragma unroll
    for (int i = 0; i < 16; i++) {
        float4 b = bv[i];
        o[4*i+0] = b.x; o[4*i+1] = b.y; o[4*i+2] = b.z; o[4*i+3] = b.w;
    }
    #pragma unroll
    for (int ch = 0; ch < 4; ch++) {
        int cbase = ch * 32;
        float h[32];
        const float4* b0v = reinterpret_cast<const float4*>(b0 + cbase);
        #pragma unroll
        for (int i = 0; i < 8; i++) {
            float4 b = b0v[i];
            h[4*i+0] = b.x; h[4*i+1] = b.y; h[4*i+2] = b.z; h[4*i+3] = b.w;
        }
        g1_accum32(a4, 16, W0, cbase, h);
        g1_accum32(d4, 16, W0 + 64*128, cbase, h);
        g1_accum32(s4, 16, W0 + 128*128, cbase, h);
        #pragma unroll
        for (int i = 0; i < 32; i++) h[i] = fmaxf(h[i], 0.0f);
        g2_accum64(sb, h, W1, cbase, 64, o);
    }
    if (valid) {
        float4* eo4 = reinterpret_cast<float4*>(edgeT + (size_t)e * 64);
        #pragma unroll
        for (int i = 0; i < 16; i++) {
            float4 t = a4[i];
            t.x += o[4*i+0]; t.y += o[4*i+1];
            t.z += o[4*i+2]; t.w += o[4*i+3];
            eo4[i] = t;
        }
    }
}

// ------------- mean aggregation (fp64, order-invariant) ---------------------

__global__ __launch_bounds__(256) void k_agg_csr(
    const float* __restrict__ edgeT, const int* __restrict__ row_off,
    const float* __restrict__ inv_cnt, float* __restrict__ aggT, int N) {
    int n = blockIdx.x * 4 + (threadIdx.x >> 6);
    int lane = threadIdx.x & 63;
    if (n >= N) return;
    int beg = row_off[n], end = row_off[n + 1];
    double s = 0.0;
    for (int idx = beg; idx < end; idx++)
        s += (double)edgeT[(size_t)idx * 64 + lane];
    aggT[(size_t)n * 64 + lane] = (float)(s * (double)inv_cnt[n]);
}

__global__ __launch_bounds__(256) void k_agg_gather(
    const float* __restrict__ edgeT, const int* __restrict__ row_off,
    const int* __restrict__ edge_list, const float* __restrict__ inv_cnt,
    float* __restrict__ aggT, int N) {
    int n = blockIdx.x * 4 + (threadIdx.x >> 6);
    int lane = threadIdx.x & 63;
    if (n >= N) return;
    int beg = row_off[n], end = row_off[n + 1];
    double s = 0.0;
    for (int idx = beg; idx < end; idx++) {
        int e = edge_list[idx];
        s += (double)edgeT[(size_t)e * 64 + lane];
    }
    aggT[(size_t)n * 64 + lane] = (float)(s * (double)inv_cnt[n]);
}

// ------------- decoder — R5 version -----------------------------------------

__global__ __launch_bounds__(256, 2) void k_decode(
    const float* __restrict__ nodeF, const float* __restrict__ embW,
    const float* __restrict__ encW0, const float* __restrict__ encW1,
    const float* __restrict__ encb1, const float* __restrict__ nodeT,
    const float* __restrict__ W0, const float* __restrict__ b0,
    const float* __restrict__ W1, const float* __restrict__ b1,
    float* __restrict__ out, int N) {
    __shared__ float sb[64 * 256];
    int t = threadIdx.x;
    int n = blockIdx.x * 256 + t;
    bool valid = n < N;
    int nc = valid ? n : N - 1;
    const float4* nf4 = reinterpret_cast<const float4*>(nodeF + (size_t)nc * 32);
    const float4* t4  = reinterpret_cast<const float4*>(nodeT + (size_t)nc * 64);
    float4 v7 = nf4[7];
    int p = (int)(v7.w + 0.5f);
    const float4* ew = reinterpret_cast<const float4*>(embW + p * 128);

    float head[64];
    const float4* ebv = reinterpret_cast<const float4*>(encb1);
    #pragma unroll
    for (int i = 0; i < 16; i++) {
        float4 b = ebv[i];
        head[4*i+0] = b.x; head[4*i+1] = b.y; head[4*i+2] = b.z; head[4*i+3] = b.w;
    }
    #pragma unroll
    for (int ch = 0; ch < 4; ch++) {
        int cbase = ch * 32;
        float h[32];
        #pragma unroll
        for (int i = 0; i < 8; i++) {
            float4 u = ew[ch*8 + i];
            h[4*i+0] = u.x; h[4*i+1] = u.y; h[4*i+2] = u.z; h[4*i+3] = u.w;
        }
        g1_accum32(nf4, 7, encW0, cbase, h);
        g1_tail3(v7.x, v7.y, v7.z, encW0 + 28*128, cbase, h);
        #pragma unroll
        for (int i = 0; i < 32; i++) h[i] = fmaxf(h[i], 0.0f);
        g2_accum64(sb, h, encW1, cbase, 128, head);
    }

    #pragma unroll
    for (int k = 0; k < 64; k++) sb[k * 256 + t] = head[k];
    __syncthreads();

    float h2[128];
    #pragma unroll
    for (int ch = 0; ch < 4; ch++) {
        int cbase = ch * 32;
        float* hc = &h2[ch * 32];
        const float4* b0v = reinterpret_cast<const float4*>(b0 + cbase);
        #pragma unroll
        for (int i = 0; i < 8; i++) {
            float4 b = b0v[i];
            hc[4*i+0] = b.x; hc[4*i+1] = b.y; hc[4*i+2] = b.z; hc[4*i+3] = b.w;
        }
        #pragma clang loop unroll(disable)
        for (int k = 0; k < 64; k++) {
            float hk = sb[k * 256 + t];
            const float4* w = reinterpret_cast<const float4*>(W0 + (size_t)k * 128 + cbase);
            #pragma unroll
            for (int cg = 0; cg < 8; cg++) {
                float4 wv = w[cg];
                hc[cg*4+0] = fmaf(hk, wv.x, hc[cg*4+0]);
                hc[cg*4+1] = fmaf(hk, wv.y, hc[cg*4+1]);
                hc[cg*4+2] = fmaf(hk, wv.z, hc[cg*4+2]);
                hc[cg*4+3] = fmaf(hk, wv.w, hc[cg*4+3]);
            }
        }
        g1_accum32(t4, 16, W0 + 64*128, cbase, hc);
    }
    __syncthreads();

    float o0 = b1[0], o1 = b1[1], o2 = b1[2];
    #pragma unroll
    for (int ch = 0; ch < 4; ch++) {
        int kb = ch * 32;
        #pragma unroll
        for (int k = 0; k < 32; k++) sb[k * 256 + t] = fmaxf(h2[kb + k], 0.0f);
        __syncthreads();
        #pragma clang loop unroll(disable)
        for (int k = 0; k < 32; k++) {
            float hk = sb[k * 256 + t];
            const float* w = W1 + (size_t)(kb + k) * 3;
            o0 = fmaf(hk, w[0], o0);
            o1 = fmaf(hk, w[1], o1);
            o2 = fmaf(hk, w[2], o2);
        }
        __syncthreads();
    }
    if (valid) {
        out[(size_t)n * 3 + 0] = o0;
        out[(size_t)n * 3 + 1] = o1;
        out[(size_t)n * 3 + 2] = o2;
    }
}

// ---------------------------------------------------------------------------

extern "C" void kernel_launch(void* const* d_in, const int* in_sizes, int n_in,
                              void* d_out, int out_size, void* d_ws, size_t ws_size,
                              hipStream_t stream) {
    const int*   edge_index = (const int*)  d_in[0];
    const float* nodeF      = (const float*)d_in[1];
    const float* edgeF      = (const float*)d_in[2];
    const float* emb        = (const float*)d_in[3];
    const float* enc_n_W0   = (const float*)d_in[4];
    const float* enc_n_b0   = (const float*)d_in[5];
    const float* enc_n_W1   = (const float*)d_in[6];
    const float* enc_n_b1   = (const float*)d_in[7];
    const float* enc_e_W0   = (const float*)d_in[8];
    const float* enc_e_b0   = (const float*)d_in[9];
    const float* enc_e_W1   = (const float*)d_in[10];
    const float* enc_e_b1   = (const float*)d_in[11];
    const float* core_e_W0  = (const float*)d_in[12];
    const float* core_e_b0  = (const float*)d_in[13];
    const float* core_e_W1  = (const float*)d_in[14];
    const float* core_e_b1  = (const float*)d_in[15];
    const float* core_n_W0  = (const float*)d_in[16];
    const float* core_n_b0  = (const float*)d_in[17];
    const float* core_n_W1  = (const float*)d_in[18];
    const float* core_n_b1  = (const float*)d_in[19];
    const float* dec_W0     = (const float*)d_in[20];
    const float* dec_b0     = (const float*)d_in[21];
    const float* dec_W1     = (const float*)d_in[22];
    const float* dec_b1     = (const float*)d_in[23];
    (void)n_in; (void)out_size;

    const int E = in_sizes[0] / 2;
    const int N = in_sizes[1] / 32;
    const int* src = edge_index;
    const int* dst = edge_index + E;

    auto al = [](size_t x) { return (x + 255) & ~(size_t)255; };
    const size_t szEdgeT = al((size_t)E * 64 * 4);
    const size_t szNodeT = al((size_t)N * 64 * 4);
    const size_t szP     = al((size_t)N * 128 * 4);
    const size_t szAgg   = al((size_t)N * 64 * 4);
    const size_t szElist = al((size_t)E * 4);
    const size_t szN4    = al((size_t)N * 4);
    const size_t szRow   = al((size_t)(N + 1) * 4);
    const size_t szEmbW  = al(2 * 128 * 4);
    const size_t base = szEdgeT + szNodeT + szElist + szRow + 3 * szN4 + szEmbW;
    const size_t needCSR = base + 2 * szElist + szP;
    const size_t needAp  = base + szP;
    const int plan = (ws_size >= needCSR) ? 0 : (ws_size >= needAp) ? 1 : 2;

    char* ws = (char*)d_ws;
    size_t off = 0;
    auto carve = [&](size_t bytes) -> char* { char* p = ws + off; off += bytes; return p; };
    float* edgeT   = (float*)carve(szEdgeT);
    float* nodeT   = (float*)carve(szNodeT);
    int*   elist   = (int*)  carve(szElist);
    int*   row_off = (int*)  carve(szRow);
    int*   counts  = (int*)  carve(szN4);
    int*   cursor  = (int*)  carve(szN4);
    float* inv_cnt = (float*)carve(szN4);
    float* embW    = (float*)carve(szEmbW);
    int *src_p = nullptr, *dst_p = nullptr;
    float *Pd = nullptr, *aggT = nullptr;
    if (plan == 0) {
        src_p = (int*)carve(szElist);
        dst_p = (int*)carve(szElist);
        Pd = (float*)carve(szP); aggT = Pd;   // lifetime-disjoint alias
    } else if (plan == 1) {
        Pd = (float*)carve(szP); aggT = Pd;
    } else {
        aggT = (float*)carve(szAgg);
    }

    int blkE = (E + 255) / 256;
    int blkN = (N + 255) / 256;
    int blkT = (E + 63) / 64;
    int blkNT = (N + 63) / 64;

    k_zero<<<(N + 255) / 256, 256, 0, stream>>>(counts, N);
    k_hist<<<blkE, 256, 0, stream>>>(dst, counts, E);
    k_scan<<<1, 1024, 0, stream>>>(counts, row_off, cursor, inv_cnt, N);
    k_fill<<<blkE, 256, 0, stream>>>(dst, cursor, elist, E);
    if (plan == 0)
        k_perm_idx<<<blkE, 256, 0, stream>>>(elist, src, dst, src_p, dst_p, E);

    k_embW<<<1, 128, 0, stream>>>(emb, enc_n_W0, enc_n_b0, embW);
    k_enc_node_tail<<<blkN, 256, 0, stream>>>(nodeF, embW, enc_n_W0, enc_n_W1,
                                              enc_n_b1, nodeT, N);
    k_enc_edge_T<<<blkT, 256, 0, stream>>>(edgeF, elist, (plan == 0) ? 1 : 0,
                                           enc_e_W0, enc_e_b0, enc_e_W1, enc_e_b1,
                                           edgeT, E);

    for (int step = 0; step < 3; step++) {
        if (plan == 0) {
            k_node_pre_d<<<blkN, 256, 0, stream>>>(nodeT, core_e_W0, core_e_b0, Pd, N);
            k_edge_core_T<<<blkT, 256, 0, stream>>>(edgeT, Pd, nodeT, src_p, dst_p,
                                                    core_e_W0, core_e_W1, core_e_b1, E);
            k_agg_csr<<<(N + 3) / 4, 256, 0, stream>>>(edgeT, row_off, inv_cnt, aggT, N);
        } else if (plan == 1) {
            k_node_pre_d<<<blkN, 256, 0, stream>>>(nodeT, core_e_W0, core_e_b0, Pd, N);
            k_edge_core_T<<<blkT, 256, 0, stream>>>(edgeT, Pd, nodeT, src, dst,
                                                    core_e_W0, core_e_W1, core_e_b1, E);
            k_agg_gather<<<(N + 3) / 4, 256, 0, stream>>>(edgeT, row_off, elist,
                                                          inv_cnt, aggT, N);
        } else {
            k_edge_core_B<<<blkE, 256, 0, stream>>>(edgeT, nodeT, src, dst,
                                                    core_e_W0, core_e_b0,
                                                    core_e_W1, core_e_b1, E);
            k_agg_gather<<<(N + 3) / 4, 256, 0, stream>>>(edgeT, row_off, elist,
                                                          inv_cnt, aggT, N);
        }
        k_node_core_T<<<blkNT, 256, 0, stream>>>(aggT, nodeT, core_n_W0, core_n_b0,
                                                 core_n_W1, core_n_b1, N);
    }
    k_decode<<<blkN, 256, 0, stream>>>(nodeF, embW, enc_n_W0, enc_n_W1, enc_n_b1,
                                       nodeT, dec_W0, dec_b0, dec_W1, dec_b1,
                                       (float*)d_out, N);
}

// Round 11
// 2719.874 us; speedup vs baseline: 1.1316x; 1.1316x over previous
//
#include <hip/hip_runtime.h>
#include <cstdint>
#include <cstddef>

// ---------------------------------------------------------------------------
// EncodeProcessDecode GNN, fp32.
// R11: revert R10's spill regression (WRITE_SIZE 200->810MB = scratch spills
// from av[4]+prefetch register bloat under the (256,3) VGPR cap). Base = R9
// (2859us). Contained changes: (a) GEMM2-only b128 H-reads (H stride 68,
// 16B-aligned; GEMM1 keeps scalar A-reads -> no register bloat), float4 A
// staging; (b) tiled k_node_pre_T (64 nodes/block, staged W) replaces
// thread-per-row Pd projection.
// Kept: CSR-permuted edge state, conflict-free mappings, W reg-prefetch,
// fp64 order-invariant aggregation, plan tiers by ws_size.
// ---------------------------------------------------------------------------

__global__ void k_zero(int* __restrict__ p, int n) {
    int i = blockIdx.x * 256 + threadIdx.x;
    if (i < n) p[i] = 0;
}

// ---------------- CSR build ----------------

__global__ void k_hist(const int* __restrict__ dst, int* __restrict__ counts, int E) {
    int e = blockIdx.x * 256 + threadIdx.x;
    if (e < E) atomicAdd(&counts[dst[e]], 1);
}

__global__ __launch_bounds__(1024) void k_scan(
    const int* __restrict__ counts, int* __restrict__ row_off,
    int* __restrict__ cursor, float* __restrict__ inv_cnt, int N) {
    __shared__ int wsum[16];
    int t = threadIdx.x;
    int wave = t >> 6, lane = t & 63;
    int carry = 0;
    for (int base = 0; base < N; base += 1024) {
        int i = base + t;
        int v = (i < N) ? counts[i] : 0;
        int s = v;
        #pragma unroll
        for (int off = 1; off < 64; off <<= 1) {
            int u = __shfl_up(s, off, 64);
            if (lane >= off) s += u;
        }
        if (lane == 63) wsum[wave] = s;
        __syncthreads();
        int wpre = 0, full = 0;
        #pragma unroll
        for (int wv = 0; wv < 16; wv++) {
            int x = wsum[wv];
            full += x;
            if (wv < wave) wpre += x;
        }
        if (i < N) {
            int excl = carry + wpre + s - v;
            row_off[i] = excl;
            cursor[i]  = excl;
            inv_cnt[i] = 1.0f / (float)((v > 0) ? v : 1);
        }
        carry += full;
        __syncthreads();
    }
    if (t == 0) row_off[N] = carry;
}

__global__ void k_fill(const int* __restrict__ dst, int* __restrict__ cursor,
                       int* __restrict__ edge_list, int E) {
    int e = blockIdx.x * 256 + threadIdx.x;
    if (e < E) {
        int pos = atomicAdd(&cursor[dst[e]], 1);
        edge_list[pos] = e;
    }
}

__global__ void k_perm_idx(const int* __restrict__ elist,
                           const int* __restrict__ src, const int* __restrict__ dst,
                           int* __restrict__ src_p, int* __restrict__ dst_p, int E) {
    int i = blockIdx.x * 256 + threadIdx.x;
    if (i < E) {
        int e = elist[i];
        src_p[i] = src[e];
        dst_p[i] = dst[e];
    }
}

// ---------------- encoder helper table ----------------

__global__ void k_embW(const float* __restrict__ emb, const float* __restrict__ W0,
                       const float* __restrict__ b0, float* __restrict__ embW) {
    int c = threadIdx.x;  // 128 threads
    #pragma unroll
    for (int p = 0; p < 2; p++) {
        float acc = b0[c];
        #pragma unroll
        for (int k = 0; k < 16; k++)
            acc = fmaf(emb[p * 16 + k], W0[(31 + k) * 128 + c], acc);
        embW[p * 128 + c] = acc;
    }
}

// ---------------- thread-per-row building blocks ----------------

__device__ __forceinline__ void g1_accum32(
    const float4* __restrict__ a4, int kk4,
    const float* __restrict__ W, int cbase, float* __restrict__ h) {
    #pragma clang loop unroll(disable)
    for (int kk = 0; kk < kk4; kk++) {
        float4 a = a4[kk];
        const float* wr = W + (size_t)kk * 4 * 128 + cbase;
        const float4* w0 = reinterpret_cast<const float4*>(wr);
        const float4* w1 = reinterpret_cast<const float4*>(wr + 128);
        const float4* w2 = reinterpret_cast<const float4*>(wr + 256);
        const float4* w3 = reinterpret_cast<const float4*>(wr + 384);
        #pragma unroll
        for (int cg = 0; cg < 8; cg++) {
            float4 p = w0[cg], q = w1[cg], r = w2[cg], s = w3[cg];
            h[cg*4+0] = fmaf(a.w, s.x, fmaf(a.z, r.x, fmaf(a.y, q.x, fmaf(a.x, p.x, h[cg*4+0]))));
            h[cg*4+1] = fmaf(a.w, s.y, fmaf(a.z, r.y, fmaf(a.y, q.y, fmaf(a.x, p.y, h[cg*4+1]))));
            h[cg*4+2] = fmaf(a.w, s.z, fmaf(a.z, r.z, fmaf(a.y, q.z, fmaf(a.x, p.z, h[cg*4+2]))));
            h[cg*4+3] = fmaf(a.w, s.w, fmaf(a.z, r.w, fmaf(a.y, q.w, fmaf(a.x, p.w, h[cg*4+3]))));
        }
    }
}

__device__ __forceinline__ void g1_tail3(
    float x, float y, float z, const float* __restrict__ W, int cbase,
    float* __restrict__ h) {
    const float4* w0 = reinterpret_cast<const float4*>(W + cbase);
    const float4* w1 = reinterpret_cast<const float4*>(W + 128 + cbase);
    const float4* w2 = reinterpret_cast<const float4*>(W + 256 + cbase);
    #pragma unroll
    for (int cg = 0; cg < 8; cg++) {
        float4 p = w0[cg], q = w1[cg], r = w2[cg];
        h[cg*4+0] = fmaf(z, r.x, fmaf(y, q.x, fmaf(x, p.x, h[cg*4+0])));
        h[cg*4+1] = fmaf(z, r.y, fmaf(y, q.y, fmaf(x, p.y, h[cg*4+1])));
        h[cg*4+2] = fmaf(z, r.z, fmaf(y, q.z, fmaf(x, p.z, h[cg*4+2])));
        h[cg*4+3] = fmaf(z, r.w, fmaf(y, q.w, fmaf(x, p.w, h[cg*4+3])));
    }
}

__device__ __forceinline__ void g2_accum64(
    float* __restrict__ sb, const float* __restrict__ hc,
    const float* __restrict__ W1, int kbase, int rs, float* __restrict__ o) {
    int t = threadIdx.x;
    #pragma unroll
    for (int k = 0; k < 32; k++) sb[k * 256 + t] = hc[k];
    __syncthreads();
    #pragma clang loop unroll(disable)
    for (int k = 0; k < 32; k++) {
        float hk = sb[k * 256 + t];
        const float4* w = reinterpret_cast<const float4*>(W1 + (size_t)(kbase + k) * rs);
        #pragma unroll
        for (int cg = 0; cg < 16; cg++) {
            float4 wv = w[cg];
            o[cg*4+0] = fmaf(hk, wv.x, o[cg*4+0]);
            o[cg*4+1] = fmaf(hk, wv.y, o[cg*4+1]);
            o[cg*4+2] = fmaf(hk, wv.z, o[cg*4+2]);
            o[cg*4+3] = fmaf(hk, wv.w, o[cg*4+3]);
        }
    }
    __syncthreads();
}

// ---------------- node encoder (tail only) — R5 version ---------------------

__global__ __launch_bounds__(256, 2) void k_enc_node_tail(
    const float* __restrict__ nodeF, const float* __restrict__ embW,
    const float* __restrict__ W0, const float* __restrict__ W1,
    const float* __restrict__ b1, float* __restrict__ nodeT, int N) {
    __shared__ float sb[32 * 256];
    int n = blockIdx.x * 256 + threadIdx.x;
    bool valid = n < N;
    int nc = valid ? n : N - 1;
    const float4* nf4 = reinterpret_cast<const float4*>(nodeF + (size_t)nc * 32);
    float4 v7 = nf4[7];
    int p = (int)(v7.w + 0.5f);
    const float4* ew = reinterpret_cast<const float4*>(embW + p * 128);

    float o[64];
    const float4* bv = reinterpret_cast<const float4*>(b1 + 64);
    #pragma unroll
    for (int i = 0; i < 16; i++) {
        float4 b = bv[i];
        o[4*i+0] = b.x; o[4*i+1] = b.y; o[4*i+2] = b.z; o[4*i+3] = b.w;
    }
    #pragma unroll
    for (int ch = 0; ch < 4; ch++) {
        int cbase = ch * 32;
        float h[32];
        #pragma unroll
        for (int i = 0; i < 8; i++) {
            float4 u = ew[ch*8 + i];
            h[4*i+0] = u.x; h[4*i+1] = u.y; h[4*i+2] = u.z; h[4*i+3] = u.w;
        }
        g1_accum32(nf4, 7, W0, cbase, h);
        g1_tail3(v7.x, v7.y, v7.z, W0 + 28*128, cbase, h);
        #pragma unroll
        for (int i = 0; i < 32; i++) h[i] = fmaxf(h[i], 0.0f);
        g2_accum64(sb, h, W1 + 64, cbase, 128, o);
    }
    if (valid) {
        float4* out4 = reinterpret_cast<float4*>(nodeT + (size_t)n * 64);
        #pragma unroll
        for (int i = 0; i < 16; i++)
            out4[i] = make_float4(o[4*i], o[4*i+1], o[4*i+2], o[4*i+3]);
    }
}

// ---------------- tiled edge encoder (R11: b128 H-reads in GEMM2) -----------

__global__ __launch_bounds__(256, 3) void k_enc_edge_T(
    const float* __restrict__ edgeF, const int* __restrict__ perm, int usePerm,
    const float* __restrict__ W0, const float* __restrict__ b0,
    const float* __restrict__ W1, const float* __restrict__ b1,
    float* __restrict__ edgeT, int E) {
    __shared__ float H[128 * 68];     // H[c][e], stride 68
    __shared__ float Wbuf[32 * 68];   // W1 chunk
    __shared__ float Xs[64 * 4];

    int t = threadIdx.x;
    int base = blockIdx.x * 64;

    if (t < 192) {
        int i = t / 3, j = t - i * 3;
        int e = base + i; int ec = (e < E) ? e : E - 1;
        int e2 = usePerm ? perm[ec] : ec;
        Xs[i * 4 + j] = edgeF[(size_t)e2 * 3 + j];
    }
    __syncthreads();

    int eg = t & 15, cg = t >> 4;
    float c1[4][8];
    {
        float4 b0a = *reinterpret_cast<const float4*>(b0 + cg * 8);
        float4 b0b = *reinterpret_cast<const float4*>(b0 + cg * 8 + 4);
        float bb[8] = {b0a.x,b0a.y,b0a.z,b0a.w,b0b.x,b0b.y,b0b.z,b0b.w};
        #pragma unroll
        for (int ie = 0; ie < 4; ie++)
            #pragma unroll
            for (int jc = 0; jc < 8; jc++) c1[ie][jc] = bb[jc];
    }
    #pragma unroll
    for (int k = 0; k < 3; k++) {
        float4 wa = *reinterpret_cast<const float4*>(W0 + k * 128 + cg * 8);
        float4 wb = *reinterpret_cast<const float4*>(W0 + k * 128 + cg * 8 + 4);
        float ww[8] = {wa.x,wa.y,wa.z,wa.w,wb.x,wb.y,wb.z,wb.w};
        #pragma unroll
        for (int ie = 0; ie < 4; ie++) {
            float a = Xs[(eg + 16 * ie) * 4 + k];
            #pragma unroll
            for (int jc = 0; jc < 8; jc++)
                c1[ie][jc] = fmaf(a, ww[jc], c1[ie][jc]);
        }
    }

    // prefetch W1 phase-0 slice into regs
    int wr_r = t >> 3, wr_cb = t & 7;
    float4 wreg2[2];
    {
        const float4* wr = reinterpret_cast<const float4*>(
            W1 + (size_t)(wr_r) * 128 + 64 + wr_cb * 8);
        wreg2[0] = wr[0]; wreg2[1] = wr[1];
    }

    #pragma unroll
    for (int ie = 0; ie < 4; ie++)
        #pragma unroll
        for (int jc = 0; jc < 8; jc++)
            H[(cg * 8 + jc) * 68 + eg + 16 * ie] = fmaxf(c1[ie][jc], 0.0f);

    int eg2 = t & 15, cg2 = t >> 4;
    float c2[4][4];
    {
        float4 bv = *reinterpret_cast<const float4*>(b1 + 64 + cg2 * 4);
        #pragma unroll
        for (int ie = 0; ie < 4; ie++) {
            c2[ie][0]=bv.x; c2[ie][1]=bv.y; c2[ie][2]=bv.z; c2[ie][3]=bv.w;
        }
    }
    #pragma clang loop unroll(disable)
    for (int phase = 0; phase < 4; phase++) {
        __syncthreads();                  // H written / prev Wbuf reads done
        {
            float* wd = Wbuf + wr_r * 68 + wr_cb * 8;
            wd[0]=wreg2[0].x; wd[1]=wreg2[0].y; wd[2]=wreg2[0].z; wd[3]=wreg2[0].w;
            wd[4]=wreg2[1].x; wd[5]=wreg2[1].y; wd[6]=wreg2[1].z; wd[7]=wreg2[1].w;
        }
        __syncthreads();
        if (phase < 3) {
            const float4* wr = reinterpret_cast<const float4*>(
                W1 + (size_t)((phase + 1) * 32 + wr_r) * 128 + 64 + wr_cb * 8);
            wreg2[0] = wr[0]; wreg2[1] = wr[1];
        }
        #pragma clang loop unroll_count(4)
        for (int k = 0; k < 32; k++) {
            int c = phase * 32 + k;
            float4 av = *reinterpret_cast<const float4*>(H + c * 68 + eg2 * 4);
            float4 b4 = *reinterpret_cast<const float4*>(Wbuf + k * 68 + cg2 * 4);
            float bb[4] = {b4.x, b4.y, b4.z, b4.w};
            float aa[4] = {av.x, av.y, av.z, av.w};
            #pragma unroll
            for (int jc = 0; jc < 4; jc++) {
                c2[0][jc] = fmaf(aa[0], bb[jc], c2[0][jc]);
                c2[1][jc] = fmaf(aa[1], bb[jc], c2[1][jc]);
                c2[2][jc] = fmaf(aa[2], bb[jc], c2[2][jc]);
                c2[3][jc] = fmaf(aa[3], bb[jc], c2[3][jc]);
            }
        }
    }
    #pragma unroll
    for (int ie = 0; ie < 4; ie++) {
        int e = base + eg2 * 4 + ie;
        if (e < E) {
            *reinterpret_cast<float4*>(edgeT + (size_t)e * 64 + cg2 * 4) =
                make_float4(c2[ie][0], c2[ie][1], c2[ie][2], c2[ie][3]);
        }
    }
}

// ------------- tiled per-step node projection (R11) -------------------------
// Pd[64n x 128c] = b0 + nodeT[64n x 64] @ W0[64:128][0:128]

__global__ __launch_bounds__(256, 4) void k_node_pre_T(
    const float* __restrict__ nodeT, const float* __restrict__ W0,
    const float* __restrict__ b0, float* __restrict__ Pd, int N) {
    __shared__ float As[64 * 68];     // A[n][k], stride 68
    __shared__ float Wbuf[32 * 132];

    int t = threadIdx.x;
    int base = blockIdx.x * 64;

    {
        int i = t >> 2, q = t & 3;
        int n = base + i; int nc = (n < N) ? n : N - 1;
        const float4* tr = reinterpret_cast<const float4*>(nodeT + (size_t)nc * 64 + q * 16);
        float4* ad = reinterpret_cast<float4*>(As + i * 68 + q * 16);
        ad[0]=tr[0]; ad[1]=tr[1]; ad[2]=tr[2]; ad[3]=tr[3];
    }

    int ng = t & 15, cg = t >> 4;
    float c[4][8];
    {
        float4 b0a = *reinterpret_cast<const float4*>(b0 + cg * 8);
        float4 b0b = *reinterpret_cast<const float4*>(b0 + cg * 8 + 4);
        float bb[8] = {b0a.x,b0a.y,b0a.z,b0a.w,b0b.x,b0b.y,b0b.z,b0b.w};
        #pragma unroll
        for (int in = 0; in < 4; in++)
            #pragma unroll
            for (int jc = 0; jc < 8; jc++) c[in][jc] = bb[jc];
    }

    int wr_r = t >> 3, wr_cb = t & 7;
    #pragma clang loop unroll(disable)
    for (int phase = 0; phase < 2; phase++) {
        __syncthreads();
        {
            const float4* wr = reinterpret_cast<const float4*>(
                W0 + (size_t)(64 + phase * 32 + wr_r) * 128 + wr_cb * 16);
            float4* wd = reinterpret_cast<float4*>(Wbuf + wr_r * 132 + wr_cb * 16);
            wd[0]=wr[0]; wd[1]=wr[1]; wd[2]=wr[2]; wd[3]=wr[3];
        }
        __syncthreads();
        int koff = phase * 32;
        #pragma clang loop unroll_count(4)
        for (int k = 0; k < 32; k++) {
            float a0 = As[(ng + 16*0)*68 + koff + k];
            float a1 = As[(ng + 16*1)*68 + koff + k];
            float a2 = As[(ng + 16*2)*68 + koff + k];
            float a3 = As[(ng + 16*3)*68 + koff + k];
            const float* wrp = Wbuf + k * 132 + cg * 8;
            float4 bq0 = *reinterpret_cast<const float4*>(wrp);
            float4 bq1 = *reinterpret_cast<const float4*>(wrp + 4);
            float bb[8] = {bq0.x,bq0.y,bq0.z,bq0.w,bq1.x,bq1.y,bq1.z,bq1.w};
            #pragma unroll
            for (int jc = 0; jc < 8; jc++) {
                c[0][jc] = fmaf(a0, bb[jc], c[0][jc]);
                c[1][jc] = fmaf(a1, bb[jc], c[1][jc]);
                c[2][jc] = fmaf(a2, bb[jc], c[2][jc]);
                c[3][jc] = fmaf(a3, bb[jc], c[3][jc]);
            }
        }
    }

    #pragma unroll
    for (int in = 0; in < 4; in++) {
        int n = base + ng + 16 * in;
        if (n < N) {
            float4* o4 = reinterpret_cast<float4*>(Pd + (size_t)n * 128 + cg * 8);
            o4[0] = make_float4(c[in][0], c[in][1], c[in][2], c[in][3]);
            o4[1] = make_float4(c[in][4], c[in][5], c[in][6], c[in][7]);
        }
    }
}

// ------------- tiled edge core (R11: b128 H-reads in GEMM2 only) ------------

__global__ __launch_bounds__(256, 3) void k_edge_core_T(
    float* __restrict__ edgeT, const float* __restrict__ Pd,
    const float* __restrict__ nodeT,
    const int* __restrict__ srcI, const int* __restrict__ dstI,
    const float* __restrict__ W0, const float* __restrict__ W1,
    const float* __restrict__ b1, int E) {
    __shared__ float Abuf[2 * 64 * 68];   // A_e | A_s (stride 68); later H[128][68]
    __shared__ float Wbuf[32 * 132];

    int t = threadIdx.x;
    int base = blockIdx.x * 64;

    // ---- stage A_e (edgeT rows) and A_s (nodeT[src] rows), float4 ----
    {
        int i = t >> 2, q = t & 3;
        int e = base + i; int ec = (e < E) ? e : E - 1;
        const float4* er = reinterpret_cast<const float4*>(edgeT + (size_t)ec * 64 + q * 16);
        int s = srcI[ec];
        const float4* sr = reinterpret_cast<const float4*>(nodeT + (size_t)s * 64 + q * 16);
        float4* ae = reinterpret_cast<float4*>(Abuf + i * 68 + q * 16);
        float4* as = reinterpret_cast<float4*>(Abuf + 64 * 68 + i * 68 + q * 16);
        #pragma unroll
        for (int j4 = 0; j4 < 4; j4++) { ae[j4] = er[j4]; as[j4] = sr[j4]; }
    }

    // ---- init C1 from Pd[dst]; edges e = eg + 16*ie ----
    int eg = t & 15, cg = t >> 4;
    float c1[4][8];
    #pragma unroll
    for (int ie = 0; ie < 4; ie++) {
        int e = base + eg + 16 * ie; int ec = (e < E) ? e : E - 1;
        int d = dstI[ec];
        const float4* pr = reinterpret_cast<const float4*>(Pd + (size_t)d * 128 + cg * 8);
        float4 p0 = pr[0], p1 = pr[1];
        c1[ie][0]=p0.x; c1[ie][1]=p0.y; c1[ie][2]=p0.z; c1[ie][3]=p0.w;
        c1[ie][4]=p1.x; c1[ie][5]=p1.y; c1[ie][6]=p1.z; c1[ie][7]=p1.w;
    }

    // ---- GEMM1: 4 phases, W rows {0,32,128,160}, reg-prefetched ----
    int wr_r = t >> 3, wr_cb = t & 7;
    float4 wreg[4];
    {
        const float4* wr = reinterpret_cast<const float4*>(
            W0 + (size_t)wr_r * 128 + wr_cb * 16);
        wreg[0]=wr[0]; wreg[1]=wr[1]; wreg[2]=wr[2]; wreg[3]=wr[3];
    }
    #pragma clang loop unroll(disable)
    for (int phase = 0; phase < 4; phase++) {
        const float* Asrc = Abuf + ((phase < 2) ? 0 : 64 * 68);
        int koff = (phase & 1) * 32;
        __syncthreads();                  // A staged (p0) / prev Wbuf reads done
        {
            float4* wd = reinterpret_cast<float4*>(Wbuf + wr_r * 132 + wr_cb * 16);
            wd[0]=wreg[0]; wd[1]=wreg[1]; wd[2]=wreg[2]; wd[3]=wreg[3];
        }
        __syncthreads();
        if (phase < 3) {
            int wrow_n = (phase + 1 < 2) ? (phase + 1) * 32 : 128 + (phase - 1) * 32;
            const float4* wr = reinterpret_cast<const float4*>(
                W0 + (size_t)(wrow_n + wr_r) * 128 + wr_cb * 16);
            wreg[0]=wr[0]; wreg[1]=wr[1]; wreg[2]=wr[2]; wreg[3]=wr[3];
        }
        #pragma clang loop unroll_count(4)
        for (int k = 0; k < 32; k++) {
            float a0 = Asrc[(eg + 16*0)*68 + koff + k];
            float a1 = Asrc[(eg + 16*1)*68 + koff + k];
            float a2 = Asrc[(eg + 16*2)*68 + koff + k];
            float a3 = Asrc[(eg + 16*3)*68 + koff + k];
            const float* wrp = Wbuf + k * 132 + cg * 8;
            float4 bq0 = *reinterpret_cast<const float4*>(wrp);
            float4 bq1 = *reinterpret_cast<const float4*>(wrp + 4);
            float bb[8] = {bq0.x,bq0.y,bq0.z,bq0.w,bq1.x,bq1.y,bq1.z,bq1.w};
            #pragma unroll
            for (int jc = 0; jc < 8; jc++) {
                c1[0][jc] = fmaf(a0, bb[jc], c1[0][jc]);
                c1[1][jc] = fmaf(a1, bb[jc], c1[1][jc]);
                c1[2][jc] = fmaf(a2, bb[jc], c1[2][jc]);
                c1[3][jc] = fmaf(a3, bb[jc], c1[3][jc]);
            }
        }
    }

    // prefetch W1 phase-0 slice (overlaps H write + barrier)
    float4 wreg2[2];
    {
        const float4* wr = reinterpret_cast<const float4*>(
            W1 + (size_t)(wr_r) * 64 + wr_cb * 8);
        wreg2[0] = wr[0]; wreg2[1] = wr[1];
    }

    __syncthreads();                      // all A reads done -> alias as H
    float* H = Abuf;                      // H[c][e], stride 68
    #pragma unroll
    for (int ie = 0; ie < 4; ie++)
        #pragma unroll
        for (int jc = 0; jc < 8; jc++)
            H[(cg*8 + jc) * 68 + eg + 16*ie] = fmaxf(c1[ie][jc], 0.0f);

    // ---- GEMM2: 4 phases, b128 H-reads ----
    int eg2 = t & 15, cg2 = t >> 4;
    float c2[4][4];
    {
        float4 bv = *reinterpret_cast<const float4*>(b1 + cg2 * 4);
        #pragma unroll
        for (int ie = 0; ie < 4; ie++) {
            c2[ie][0]=bv.x; c2[ie][1]=bv.y; c2[ie][2]=bv.z; c2[ie][3]=bv.w;
        }
    }
    #pragma clang loop unroll(disable)
    for (int phase = 0; phase < 4; phase++) {
        __syncthreads();                  // H written (p0) / prev Wbuf reads done
        {
            float* wd = Wbuf + wr_r * 68 + wr_cb * 8;
            wd[0]=wreg2[0].x; wd[1]=wreg2[0].y; wd[2]=wreg2[0].z; wd[3]=wreg2[0].w;
            wd[4]=wreg2[1].x; wd[5]=wreg2[1].y; wd[6]=wreg2[1].z; wd[7]=wreg2[1].w;
        }
        __syncthreads();
        if (phase < 3) {
            const float4* wr = reinterpret_cast<const float4*>(
                W1 + (size_t)((phase + 1) * 32 + wr_r) * 64 + wr_cb * 8);
            wreg2[0] = wr[0]; wreg2[1] = wr[1];
        }
        #pragma clang loop unroll_count(4)
        for (int k = 0; k < 32; k++) {
            int c = phase * 32 + k;
            float4 av = *reinterpret_cast<const float4*>(H + c * 68 + eg2 * 4);
            float4 b4 = *reinterpret_cast<const float4*>(Wbuf + k * 68 + cg2 * 4);
            float bb[4] = {b4.x, b4.y, b4.z, b4.w};
            float aa[4] = {av.x, av.y, av.z, av.w};
            #pragma unroll
            for (int jc = 0; jc < 4; jc++) {
                c2[0][jc] = fmaf(aa[0], bb[jc], c2[0][jc]);
                c2[1][jc] = fmaf(aa[1], bb[jc], c2[1][jc]);
                c2[2][jc] = fmaf(aa[2], bb[jc], c2[2][jc]);
                c2[3][jc] = fmaf(aa[3], bb[jc], c2[3][jc]);
            }
        }
    }

    #pragma unroll
    for (int ie = 0; ie < 4; ie++) {
        int e = base + eg2 * 4 + ie;
        if (e < E) {
            float4* er = reinterpret_cast<float4*>(edgeT + (size_t)e * 64 + cg2 * 4);
            float4 old = *er;
            old.x += c2[ie][0]; old.y += c2[ie][1];
            old.z += c2[ie][2]; old.w += c2[ie][3];
            *er = old;
        }
    }
}

// ------------- tiled node core (R11: b128 H-reads in GEMM2) -----------------

__global__ __launch_bounds__(256, 3) void k_node_core_T(
    const float* __restrict__ aggT, float* __restrict__ nodeT,
    const float* __restrict__ W0, const float* __restrict__ b0,
    const float* __restrict__ W1, const float* __restrict__ b1, int N) {
    __shared__ float Abuf[64 * 136];      // A[n][k] stride 132; H[128][68] = 8704
    __shared__ float Wbuf[32 * 132];

    int t = threadIdx.x;
    int base = blockIdx.x * 64;

    {
        int i = t >> 2, q = t & 3;
        int n = base + i; int nc = (n < N) ? n : N - 1;
        const float4* gr = reinterpret_cast<const float4*>(aggT + (size_t)nc * 64 + q * 16);
        const float4* tr = reinterpret_cast<const float4*>(nodeT + (size_t)nc * 64 + q * 16);
        float4* ag = reinterpret_cast<float4*>(Abuf + i * 132 + q * 16);
        float4* at = reinterpret_cast<float4*>(Abuf + i * 132 + 64 + q * 16);
        #pragma unroll
        for (int j4 = 0; j4 < 4; j4++) { ag[j4] = gr[j4]; at[j4] = tr[j4]; }
    }

    int ng = t & 15, cg = t >> 4;
    float c1[4][8];
    {
        float4 b0a = *reinterpret_cast<const float4*>(b0 + cg * 8);
        float4 b0b = *reinterpret_cast<const float4*>(b0 + cg * 8 + 4);
        float bb[8] = {b0a.x,b0a.y,b0a.z,b0a.w,b0b.x,b0b.y,b0b.z,b0b.w};
        #pragma unroll
        for (int in = 0; in < 4; in++)
            #pragma unroll
            for (int jc = 0; jc < 8; jc++) c1[in][jc] = bb[jc];
    }

    int wr_r = t >> 3, wr_cb = t & 7;
    float4 wreg[4];
    {
        const float4* wr = reinterpret_cast<const float4*>(
            W0 + (size_t)wr_r * 128 + wr_cb * 16);
        wreg[0]=wr[0]; wreg[1]=wr[1]; wreg[2]=wr[2]; wreg[3]=wr[3];
    }
    #pragma clang loop unroll(disable)
    for (int phase = 0; phase < 4; phase++) {
        int koff = phase * 32;
        __syncthreads();
        {
            float4* wd = reinterpret_cast<float4*>(Wbuf + wr_r * 132 + wr_cb * 16);
            wd[0]=wreg[0]; wd[1]=wreg[1]; wd[2]=wreg[2]; wd[3]=wreg[3];
        }
        __syncthreads();
        if (phase < 3) {
            const float4* wr = reinterpret_cast<const float4*>(
                W0 + (size_t)((phase + 1) * 32 + wr_r) * 128 + wr_cb * 16);
            wreg[0]=wr[0]; wreg[1]=wr[1]; wreg[2]=wr[2]; wreg[3]=wr[3];
        }
        #pragma clang loop unroll_count(4)
        for (int k = 0; k < 32; k++) {
            float a0 = Abuf[(ng + 16*0)*132 + koff + k];
            float a1 = Abuf[(ng + 16*1)*132 + koff + k];
            float a2 = Abuf[(ng + 16*2)*132 + koff + k];
            float a3 = Abuf[(ng + 16*3)*132 + koff + k];
            const float* wrp = Wbuf + k * 132 + cg * 8;
            float4 bq0 = *reinterpret_cast<const float4*>(wrp);
            float4 bq1 = *reinterpret_cast<const float4*>(wrp + 4);
            float bb[8] = {bq0.x,bq0.y,bq0.z,bq0.w,bq1.x,bq1.y,bq1.z,bq1.w};
            #pragma unroll
            for (int jc = 0; jc < 8; jc++) {
                c1[0][jc] = fmaf(a0, bb[jc], c1[0][jc]);
                c1[1][jc] = fmaf(a1, bb[jc], c1[1][jc]);
                c1[2][jc] = fmaf(a2, bb[jc], c1[2][jc]);
                c1[3][jc] = fmaf(a3, bb[jc], c1[3][jc]);
            }
        }
    }

    float4 wreg2[2];
    {
        const float4* wr = reinterpret_cast<const float4*>(
            W1 + (size_t)wr_r * 64 + wr_cb * 8);
        wreg2[0] = wr[0]; wreg2[1] = wr[1];
    }

    __syncthreads();
    float* H = Abuf;                      // H[c][n], stride 68
    #pragma unroll
    for (int in = 0; in < 4; in++)
        #pragma unroll
        for (int jc = 0; jc < 8; jc++)
            H[(cg*8 + jc) * 68 + ng + 16*in] = fmaxf(c1[in][jc], 0.0f);

    int ng2 = t & 15, cg2 = t >> 4;
    float c2[4][4];
    {
        float4 bv = *reinterpret_cast<const float4*>(b1 + cg2 * 4);
        #pragma unroll
        for (int in = 0; in < 4; in++) {
            c2[in][0]=bv.x; c2[in][1]=bv.y; c2[in][2]=bv.z; c2[in][3]=bv.w;
        }
    }
    #pragma clang loop unroll(disable)
    for (int phase = 0; phase < 4; phase++) {
        __syncthreads();
        {
            float* wd = Wbuf + wr_r * 68 + wr_cb * 8;
            wd[0]=wreg2[0].x; wd[1]=wreg2[0].y; wd[2]=wreg2[0].z; wd[3]=wreg2[0].w;
            wd[4]=wreg2[1].x; wd[5]=wreg2[1].y; wd[6]=wreg2[1].z; wd[7]=wreg2[1].w;
        }
        __syncthreads();
        if (phase < 3) {
            const float4* wr = reinterpret_cast<const float4*>(
                W1 + (size_t)((phase + 1) * 32 + wr_r) * 64 + wr_cb * 8);
            wreg2[0] = wr[0]; wreg2[1] = wr[1];
        }
        #pragma clang loop unroll_count(4)
        for (int k = 0; k < 32; k++) {
            int c = phase * 32 + k;
            float4 av = *reinterpret_cast<const float4*>(H + c * 68 + ng2 * 4);
            float4 b4 = *reinterpret_cast<const float4*>(Wbuf + k * 68 + cg2 * 4);
            float bb[4] = {b4.x, b4.y, b4.z, b4.w};
            float aa[4] = {av.x, av.y, av.z, av.w};
            #pragma unroll
            for (int jc = 0; jc < 4; jc++) {
                c2[0][jc] = fmaf(aa[0], bb[jc], c2[0][jc]);
                c2[1][jc] = fmaf(aa[1], bb[jc], c2[1][jc]);
                c2[2][jc] = fmaf(aa[2], bb[jc], c2[2][jc]);
                c2[3][jc] = fmaf(aa[3], bb[jc], c2[3][jc]);
            }
        }
    }

    #pragma unroll
    for (int in = 0; in < 4; in++) {
        int n = base + ng2 * 4 + in;
        if (n < N) {
            float4* nr = reinterpret_cast<float4*>(nodeT + (size_t)n * 64 + cg2 * 4);
            float4 old = *nr;
            old.x += c2[in][0]; old.y += c2[in][1];
            old.z += c2[in][2]; old.w += c2[in][3];
            *nr = old;
        }
    }
}

// ------------- plan B edge core (all inline, original order) ----------------

__global__ __launch_bounds__(256, 2) void k_edge_core_B(
    float* __restrict__ edgeT, const float* __restrict__ nodeT,
    const int* __restrict__ src, const int* __restrict__ dst,
    const float* __restrict__ W0, const float* __restrict__ b0,
    const float* __restrict__ W1, const float* __restrict__ b1, int E) {
    __shared__ float sb[32 * 256];
    int e = blockIdx.x * 256 + threadIdx.x;
    bool valid = e < E;
    int ec = valid ? e : E - 1;
    int d = dst[ec], s = src[ec];
    const float4* a4 = reinterpret_cast<const float4*>(edgeT + (size_t)ec * 64);
    const float4* d4 = reinterpret_cast<const float4*>(nodeT + (size_t)d * 64);
    const float4* s4 = reinterpret_cast<const float4*>(nodeT + (size_t)s * 64);

    float o[64];
    const float4* bv = reinterpret_cast<const float4*>(b1);
    #pragma unroll
    for (int i = 0; i < 16; i++) {
        float4 b = bv[i];
        o[4*i+0] = b.x; o[4*i+1] = b.y; o[4*i+2] = b.z; o[4*i+3] = b.w;
    }
    #pragma unroll
    for (int ch = 0; ch < 4; ch++) {
        int cbase = ch * 32;
        float h[32];
        const float4* b0v = reinterpret_cast<const float4*>(b0 + cbase);
        #pragma unroll
        for (int i = 0; i < 8; i++) {
            float4 b = b0v[i];
            h[4*i+0] = b.x; h[4*i+1] = b.y; h[4*i+2] = b.z; h[4*i+3] = b.w;
        }
        g1_accum32(a4, 16, W0, cbase, h);
        g1_accum32(d4, 16, W0 + 64*128, cbase, h);
        g1_accum32(s4, 16, W0 + 128*128, cbase, h);
        #pragma unroll
        for (int i = 0; i < 32; i++) h[i] = fmaxf(h[i], 0.0f);
        g2_accum64(sb, h, W1, cbase, 64, o);
    }
    if (valid) {
        float4* eo4 = reinterpret_cast<float4*>(edgeT + (size_t)e * 64);
        #pragma unroll
        for (int i = 0; i < 16; i++) {
            float4 t = a4[i];
            t.x += o[4*i+0]; t.y += o[4*i+1];
            t.z += o[4*i+2]; t.w += o[4*i+3];
            eo4[i] = t;
        }
    }
}

// ------------- mean aggregation (fp64, order-invariant) ---------------------

__global__ __launch_bounds__(256) void k_agg_csr(
    const float* __restrict__ edgeT, const int* __restrict__ row_off,
    const float* __restrict__ inv_cnt, float* __restrict__ aggT, int N) {
    int n = blockIdx.x * 4 + (threadIdx.x >> 6);
    int lane = threadIdx.x & 63;
    if (n >= N) return;
    int beg = row_off[n], end = row_off[n + 1];
    double s = 0.0;
    for (int idx = beg; idx < end; idx++)
        s += (double)edgeT[(size_t)idx * 64 + lane];
    aggT[(size_t)n * 64 + lane] = (float)(s * (double)inv_cnt[n]);
}

__global__ __launch_bounds__(256) void k_agg_gather(
    const float* __restrict__ edgeT, const int* __restrict__ row_off,
    const int* __restrict__ edge_list, const float* __restrict__ inv_cnt,
    float* __restrict__ aggT, int N) {
    int n = blockIdx.x * 4 + (threadIdx.x >> 6);
    int lane = threadIdx.x & 63;
    if (n >= N) return;
    int beg = row_off[n], end = row_off[n + 1];
    double s = 0.0;
    for (int idx = beg; idx < end; idx++) {
        int e = edge_list[idx];
        s += (double)edgeT[(size_t)e * 64 + lane];
    }
    aggT[(size_t)n * 64 + lane] = (float)(s * (double)inv_cnt[n]);
}

// ------------- decoder — R5 version -----------------------------------------

__global__ __launch_bounds__(256, 2) void k_decode(
    const float* __restrict__ nodeF, const float* __restrict__ embW,
    const float* __restrict__ encW0, const float* __restrict__ encW1,
    const float* __restrict__ encb1, const float* __restrict__ nodeT,
    const float* __restrict__ W0, const float* __restrict__ b0,
    const float* __restrict__ W1, const float* __restrict__ b1,
    float* __restrict__ out, int N) {
    __shared__ float sb[64 * 256];
    int t = threadIdx.x;
    int n = blockIdx.x * 256 + t;
    bool valid = n < N;
    int nc = valid ? n : N - 1;
    const float4* nf4 = reinterpret_cast<const float4*>(nodeF + (size_t)nc * 32);
    const float4* t4  = reinterpret_cast<const float4*>(nodeT + (size_t)nc * 64);
    float4 v7 = nf4[7];
    int p = (int)(v7.w + 0.5f);
    const float4* ew = reinterpret_cast<const float4*>(embW + p * 128);

    float head[64];
    const float4* ebv = reinterpret_cast<const float4*>(encb1);
    #pragma unroll
    for (int i = 0; i < 16; i++) {
        float4 b = ebv[i];
        head[4*i+0] = b.x; head[4*i+1] = b.y; head[4*i+2] = b.z; head[4*i+3] = b.w;
    }
    #pragma unroll
    for (int ch = 0; ch < 4; ch++) {
        int cbase = ch * 32;
        float h[32];
        #pragma unroll
        for (int i = 0; i < 8; i++) {
            float4 u = ew[ch*8 + i];
            h[4*i+0] = u.x; h[4*i+1] = u.y; h[4*i+2] = u.z; h[4*i+3] = u.w;
        }
        g1_accum32(nf4, 7, encW0, cbase, h);
        g1_tail3(v7.x, v7.y, v7.z, encW0 + 28*128, cbase, h);
        #pragma unroll
        for (int i = 0; i < 32; i++) h[i] = fmaxf(h[i], 0.0f);
        g2_accum64(sb, h, encW1, cbase, 128, head);
    }

    #pragma unroll
    for (int k = 0; k < 64; k++) sb[k * 256 + t] = head[k];
    __syncthreads();

    float h2[128];
    #pragma unroll
    for (int ch = 0; ch < 4; ch++) {
        int cbase = ch * 32;
        float* hc = &h2[ch * 32];
        const float4* b0v = reinterpret_cast<const float4*>(b0 + cbase);
        #pragma unroll
        for (int i = 0; i < 8; i++) {
            float4 b = b0v[i];
            hc[4*i+0] = b.x; hc[4*i+1] = b.y; hc[4*i+2] = b.z; hc[4*i+3] = b.w;
        }
        #pragma clang loop unroll(disable)
        for (int k = 0; k < 64; k++) {
            float hk = sb[k * 256 + t];
            const float4* w = reinterpret_cast<const float4*>(W0 + (size_t)k * 128 + cbase);
            #pragma unroll
            for (int cg = 0; cg < 8; cg++) {
                float4 wv = w[cg];
                hc[cg*4+0] = fmaf(hk, wv.x, hc[cg*4+0]);
                hc[cg*4+1] = fmaf(hk, wv.y, hc[cg*4+1]);
                hc[cg*4+2] = fmaf(hk, wv.z, hc[cg*4+2]);
                hc[cg*4+3] = fmaf(hk, wv.w, hc[cg*4+3]);
            }
        }
        g1_accum32(t4, 16, W0 + 64*128, cbase, hc);
    }
    __syncthreads();

    float o0 = b1[0], o1 = b1[1], o2 = b1[2];
    #pragma unroll
    for (int ch = 0; ch < 4; ch++) {
        int kb = ch * 32;
        #pragma unroll
        for (int k = 0; k < 32; k++) sb[k * 256 + t] = fmaxf(h2[kb + k], 0.0f);
        __syncthreads();
        #pragma clang loop unroll(disable)
        for (int k = 0; k < 32; k++) {
            float hk = sb[k * 256 + t];
            const float* w = W1 + (size_t)(kb + k) * 3;
            o0 = fmaf(hk, w[0], o0);
            o1 = fmaf(hk, w[1], o1);
            o2 = fmaf(hk, w[2], o2);
        }
        __syncthreads();
    }
    if (valid) {
        out[(size_t)n * 3 + 0] = o0;
        out[(size_t)n * 3 + 1] = o1;
        out[(size_t)n * 3 + 2] = o2;
    }
}

// ---------------------------------------------------------------------------

extern "C" void kernel_launch(void* const* d_in, const int* in_sizes, int n_in,
                              void* d_out, int out_size, void* d_ws, size_t ws_size,
                              hipStream_t stream) {
    const int*   edge_index = (const int*)  d_in[0];
    const float* nodeF      = (const float*)d_in[1];
    const float* edgeF      = (const float*)d_in[2];
    const float* emb        = (const float*)d_in[3];
    const float* enc_n_W0   = (const float*)d_in[4];
    const float* enc_n_b0   = (const float*)d_in[5];
    const float* enc_n_W1   = (const float*)d_in[6];
    const float* enc_n_b1   = (const float*)d_in[7];
    const float* enc_e_W0   = (const float*)d_in[8];
    const float* enc_e_b0   = (const float*)d_in[9];
    const float* enc_e_W1   = (const float*)d_in[10];
    const float* enc_e_b1   = (const float*)d_in[11];
    const float* core_e_W0  = (const float*)d_in[12];
    const float* core_e_b0  = (const float*)d_in[13];
    const float* core_e_W1  = (const float*)d_in[14];
    const float* core_e_b1  = (const float*)d_in[15];
    const float* core_n_W0  = (const float*)d_in[16];
    const float* core_n_b0  = (const float*)d_in[17];
    const float* core_n_W1  = (const float*)d_in[18];
    const float* core_n_b1  = (const float*)d_in[19];
    const float* dec_W0     = (const float*)d_in[20];
    const float* dec_b0     = (const float*)d_in[21];
    const float* dec_W1     = (const float*)d_in[22];
    const float* dec_b1     = (const float*)d_in[23];
    (void)n_in; (void)out_size;

    const int E = in_sizes[0] / 2;
    const int N = in_sizes[1] / 32;
    const int* src = edge_index;
    const int* dst = edge_index + E;

    auto al = [](size_t x) { return (x + 255) & ~(size_t)255; };
    const size_t szEdgeT = al((size_t)E * 64 * 4);
    const size_t szNodeT = al((size_t)N * 64 * 4);
    const size_t szP     = al((size_t)N * 128 * 4);
    const size_t szAgg   = al((size_t)N * 64 * 4);
    const size_t szElist = al((size_t)E * 4);
    const size_t szN4    = al((size_t)N * 4);
    const size_t szRow   = al((size_t)(N + 1) * 4);
    const size_t szEmbW  = al(2 * 128 * 4);
    const size_t base = szEdgeT + szNodeT + szElist + szRow + 3 * szN4 + szEmbW;
    const size_t needCSR = base + 2 * szElist + szP;
    const size_t needAp  = base + szP;
    const int plan = (ws_size >= needCSR) ? 0 : (ws_size >= needAp) ? 1 : 2;

    char* ws = (char*)d_ws;
    size_t off = 0;
    auto carve = [&](size_t bytes) -> char* { char* p = ws + off; off += bytes; return p; };
    float* edgeT   = (float*)carve(szEdgeT);
    float* nodeT   = (float*)carve(szNodeT);
    int*   elist   = (int*)  carve(szElist);
    int*   row_off = (int*)  carve(szRow);
    int*   counts  = (int*)  carve(szN4);
    int*   cursor  = (int*)  carve(szN4);
    float* inv_cnt = (float*)carve(szN4);
    float* embW    = (float*)carve(szEmbW);
    int *src_p = nullptr, *dst_p = nullptr;
    float *Pd = nullptr, *aggT = nullptr;
    if (plan == 0) {
        src_p = (int*)carve(szElist);
        dst_p = (int*)carve(szElist);
        Pd = (float*)carve(szP); aggT = Pd;   // lifetime-disjoint alias
    } else if (plan == 1) {
        Pd = (float*)carve(szP); aggT = Pd;
    } else {
        aggT = (float*)carve(szAgg);
    }

    int blkE = (E + 255) / 256;
    int blkN = (N + 255) / 256;
    int blkT = (E + 63) / 64;
    int blkNT = (N + 63) / 64;

    k_zero<<<(N + 255) / 256, 256, 0, stream>>>(counts, N);
    k_hist<<<blkE, 256, 0, stream>>>(dst, counts, E);
    k_scan<<<1, 1024, 0, stream>>>(counts, row_off, cursor, inv_cnt, N);
    k_fill<<<blkE, 256, 0, stream>>>(dst, cursor, elist, E);
    if (plan == 0)
        k_perm_idx<<<blkE, 256, 0, stream>>>(elist, src, dst, src_p, dst_p, E);

    k_embW<<<1, 128, 0, stream>>>(emb, enc_n_W0, enc_n_b0, embW);
    k_enc_node_tail<<<blkN, 256, 0, stream>>>(nodeF, embW, enc_n_W0, enc_n_W1,
                                              enc_n_b1, nodeT, N);
    k_enc_edge_T<<<blkT, 256, 0, stream>>>(edgeF, elist, (plan == 0) ? 1 : 0,
                                           enc_e_W0, enc_e_b0, enc_e_W1, enc_e_b1,
                                           edgeT, E);

    for (int step = 0; step < 3; step++) {
        if (plan == 0) {
            k_node_pre_T<<<blkNT, 256, 0, stream>>>(nodeT, core_e_W0, core_e_b0, Pd, N);
            k_edge_core_T<<<blkT, 256, 0, stream>>>(edgeT, Pd, nodeT, src_p, dst_p,
                                                    core_e_W0, core_e_W1, core_e_b1, E);
            k_agg_csr<<<(N + 3) / 4, 256, 0, stream>>>(edgeT, row_off, inv_cnt, aggT, N);
        } else if (plan == 1) {
            k_node_pre_T<<<blkNT, 256, 0, stream>>>(nodeT, core_e_W0, core_e_b0, Pd, N);
            k_edge_core_T<<<blkT, 256, 0, stream>>>(edgeT, Pd, nodeT, src, dst,
                                                    core_e_W0, core_e_W1, core_e_b1, E);
            k_agg_gather<<<(N + 3) / 4, 256, 0, stream>>>(edgeT, row_off, elist,
                                                          inv_cnt, aggT, N);
        } else {
            k_edge_core_B<<<blkE, 256, 0, stream>>>(edgeT, nodeT, src, dst,
                                                    core_e_W0, core_e_b0,
                                                    core_e_W1, core_e_b1, E);
            k_agg_gather<<<(N + 3) / 4, 256, 0, stream>>>(edgeT, row_off, elist,
                                                          inv_cnt, aggT, N);
        }
        k_node_core_T<<<blkNT, 256, 0, stream>>>(aggT, nodeT, core_n_W0, core_n_b0,
                                                 core_n_W1, core_n_b1, N);
    }
    k_decode<<<blkN, 256, 0, stream>>>(nodeF, embW, enc_n_W0, enc_n_W1, enc_n_b1,
                                       nodeT, dec_W0, dec_b0, dec_W1, dec_b1,
                                       (float*)d_out, N);
}

// Round 12
// 2685.502 us; speedup vs baseline: 1.1461x; 1.0128x over previous
//
#include <hip/hip_runtime.h>
#include <cstdint>
#include <cstddef>

// ---------------------------------------------------------------------------
// EncodeProcessDecode GNN, fp32.
// R12: de-spill GEMM2. R11 profile showed WRITE_SIZE 503MB vs 200 ideal on
// k_edge_core_T (scratch spill round-trip ~420MB/dispatch) introduced by the
// b128-H GEMM2's aa[]/bb[] temp arrays under the (256,3) VGPR cap. GEMM2
// inner loops now use direct component FMAs (no temp arrays). Everything
// else identical to R11 (2720us): b128 H-reads stride 68, tiled node_pre,
// CSR-permuted edge state, conflict-free mappings, W reg-prefetch, fp64
// order-invariant aggregation, plan tiers by ws_size.
// ---------------------------------------------------------------------------

__global__ void k_zero(int* __restrict__ p, int n) {
    int i = blockIdx.x * 256 + threadIdx.x;
    if (i < n) p[i] = 0;
}

// ---------------- CSR build ----------------

__global__ void k_hist(const int* __restrict__ dst, int* __restrict__ counts, int E) {
    int e = blockIdx.x * 256 + threadIdx.x;
    if (e < E) atomicAdd(&counts[dst[e]], 1);
}

__global__ __launch_bounds__(1024) void k_scan(
    const int* __restrict__ counts, int* __restrict__ row_off,
    int* __restrict__ cursor, float* __restrict__ inv_cnt, int N) {
    __shared__ int wsum[16];
    int t = threadIdx.x;
    int wave = t >> 6, lane = t & 63;
    int carry = 0;
    for (int base = 0; base < N; base += 1024) {
        int i = base + t;
        int v = (i < N) ? counts[i] : 0;
        int s = v;
        #pragma unroll
        for (int off = 1; off < 64; off <<= 1) {
            int u = __shfl_up(s, off, 64);
            if (lane >= off) s += u;
        }
        if (lane == 63) wsum[wave] = s;
        __syncthreads();
        int wpre = 0, full = 0;
        #pragma unroll
        for (int wv = 0; wv < 16; wv++) {
            int x = wsum[wv];
            full += x;
            if (wv < wave) wpre += x;
        }
        if (i < N) {
            int excl = carry + wpre + s - v;
            row_off[i] = excl;
            cursor[i]  = excl;
            inv_cnt[i] = 1.0f / (float)((v > 0) ? v : 1);
        }
        carry += full;
        __syncthreads();
    }
    if (t == 0) row_off[N] = carry;
}

__global__ void k_fill(const int* __restrict__ dst, int* __restrict__ cursor,
                       int* __restrict__ edge_list, int E) {
    int e = blockIdx.x * 256 + threadIdx.x;
    if (e < E) {
        int pos = atomicAdd(&cursor[dst[e]], 1);
        edge_list[pos] = e;
    }
}

__global__ void k_perm_idx(const int* __restrict__ elist,
                           const int* __restrict__ src, const int* __restrict__ dst,
                           int* __restrict__ src_p, int* __restrict__ dst_p, int E) {
    int i = blockIdx.x * 256 + threadIdx.x;
    if (i < E) {
        int e = elist[i];
        src_p[i] = src[e];
        dst_p[i] = dst[e];
    }
}

// ---------------- encoder helper table ----------------

__global__ void k_embW(const float* __restrict__ emb, const float* __restrict__ W0,
                       const float* __restrict__ b0, float* __restrict__ embW) {
    int c = threadIdx.x;  // 128 threads
    #pragma unroll
    for (int p = 0; p < 2; p++) {
        float acc = b0[c];
        #pragma unroll
        for (int k = 0; k < 16; k++)
            acc = fmaf(emb[p * 16 + k], W0[(31 + k) * 128 + c], acc);
        embW[p * 128 + c] = acc;
    }
}

// ---------------- thread-per-row building blocks ----------------

__device__ __forceinline__ void g1_accum32(
    const float4* __restrict__ a4, int kk4,
    const float* __restrict__ W, int cbase, float* __restrict__ h) {
    #pragma clang loop unroll(disable)
    for (int kk = 0; kk < kk4; kk++) {
        float4 a = a4[kk];
        const float* wr = W + (size_t)kk * 4 * 128 + cbase;
        const float4* w0 = reinterpret_cast<const float4*>(wr);
        const float4* w1 = reinterpret_cast<const float4*>(wr + 128);
        const float4* w2 = reinterpret_cast<const float4*>(wr + 256);
        const float4* w3 = reinterpret_cast<const float4*>(wr + 384);
        #pragma unroll
        for (int cg = 0; cg < 8; cg++) {
            float4 p = w0[cg], q = w1[cg], r = w2[cg], s = w3[cg];
            h[cg*4+0] = fmaf(a.w, s.x, fmaf(a.z, r.x, fmaf(a.y, q.x, fmaf(a.x, p.x, h[cg*4+0]))));
            h[cg*4+1] = fmaf(a.w, s.y, fmaf(a.z, r.y, fmaf(a.y, q.y, fmaf(a.x, p.y, h[cg*4+1]))));
            h[cg*4+2] = fmaf(a.w, s.z, fmaf(a.z, r.z, fmaf(a.y, q.z, fmaf(a.x, p.z, h[cg*4+2]))));
            h[cg*4+3] = fmaf(a.w, s.w, fmaf(a.z, r.w, fmaf(a.y, q.w, fmaf(a.x, p.w, h[cg*4+3]))));
        }
    }
}

__device__ __forceinline__ void g1_tail3(
    float x, float y, float z, const float* __restrict__ W, int cbase,
    float* __restrict__ h) {
    const float4* w0 = reinterpret_cast<const float4*>(W + cbase);
    const float4* w1 = reinterpret_cast<const float4*>(W + 128 + cbase);
    const float4* w2 = reinterpret_cast<const float4*>(W + 256 + cbase);
    #pragma unroll
    for (int cg = 0; cg < 8; cg++) {
        float4 p = w0[cg], q = w1[cg], r = w2[cg];
        h[cg*4+0] = fmaf(z, r.x, fmaf(y, q.x, fmaf(x, p.x, h[cg*4+0])));
        h[cg*4+1] = fmaf(z, r.y, fmaf(y, q.y, fmaf(x, p.y, h[cg*4+1])));
        h[cg*4+2] = fmaf(z, r.z, fmaf(y, q.z, fmaf(x, p.z, h[cg*4+2])));
        h[cg*4+3] = fmaf(z, r.w, fmaf(y, q.w, fmaf(x, p.w, h[cg*4+3])));
    }
}

__device__ __forceinline__ void g2_accum64(
    float* __restrict__ sb, const float* __restrict__ hc,
    const float* __restrict__ W1, int kbase, int rs, float* __restrict__ o) {
    int t = threadIdx.x;
    #pragma unroll
    for (int k = 0; k < 32; k++) sb[k * 256 + t] = hc[k];
    __syncthreads();
    #pragma clang loop unroll(disable)
    for (int k = 0; k < 32; k++) {
        float hk = sb[k * 256 + t];
        const float4* w = reinterpret_cast<const float4*>(W1 + (size_t)(kbase + k) * rs);
        #pragma unroll
        for (int cg = 0; cg < 16; cg++) {
            float4 wv = w[cg];
            o[cg*4+0] = fmaf(hk, wv.x, o[cg*4+0]);
            o[cg*4+1] = fmaf(hk, wv.y, o[cg*4+1]);
            o[cg*4+2] = fmaf(hk, wv.z, o[cg*4+2]);
            o[cg*4+3] = fmaf(hk, wv.w, o[cg*4+3]);
        }
    }
    __syncthreads();
}

// GEMM2 inner 4x4 micro-kernel, no temp arrays (de-spill)
#define G2_FMA16(av, b4, c2)                           \
    c2[0][0] = fmaf(av.x, b4.x, c2[0][0]);             \
    c2[0][1] = fmaf(av.x, b4.y, c2[0][1]);             \
    c2[0][2] = fmaf(av.x, b4.z, c2[0][2]);             \
    c2[0][3] = fmaf(av.x, b4.w, c2[0][3]);             \
    c2[1][0] = fmaf(av.y, b4.x, c2[1][0]);             \
    c2[1][1] = fmaf(av.y, b4.y, c2[1][1]);             \
    c2[1][2] = fmaf(av.y, b4.z, c2[1][2]);             \
    c2[1][3] = fmaf(av.y, b4.w, c2[1][3]);             \
    c2[2][0] = fmaf(av.z, b4.x, c2[2][0]);             \
    c2[2][1] = fmaf(av.z, b4.y, c2[2][1]);             \
    c2[2][2] = fmaf(av.z, b4.z, c2[2][2]);             \
    c2[2][3] = fmaf(av.z, b4.w, c2[2][3]);             \
    c2[3][0] = fmaf(av.w, b4.x, c2[3][0]);             \
    c2[3][1] = fmaf(av.w, b4.y, c2[3][1]);             \
    c2[3][2] = fmaf(av.w, b4.z, c2[3][2]);             \
    c2[3][3] = fmaf(av.w, b4.w, c2[3][3]);

// ---------------- node encoder (tail only) — R5 version ---------------------

__global__ __launch_bounds__(256, 2) void k_enc_node_tail(
    const float* __restrict__ nodeF, const float* __restrict__ embW,
    const float* __restrict__ W0, const float* __restrict__ W1,
    const float* __restrict__ b1, float* __restrict__ nodeT, int N) {
    __shared__ float sb[32 * 256];
    int n = blockIdx.x * 256 + threadIdx.x;
    bool valid = n < N;
    int nc = valid ? n : N - 1;
    const float4* nf4 = reinterpret_cast<const float4*>(nodeF + (size_t)nc * 32);
    float4 v7 = nf4[7];
    int p = (int)(v7.w + 0.5f);
    const float4* ew = reinterpret_cast<const float4*>(embW + p * 128);

    float o[64];
    const float4* bv = reinterpret_cast<const float4*>(b1 + 64);
    #pragma unroll
    for (int i = 0; i < 16; i++) {
        float4 b = bv[i];
        o[4*i+0] = b.x; o[4*i+1] = b.y; o[4*i+2] = b.z; o[4*i+3] = b.w;
    }
    #pragma unroll
    for (int ch = 0; ch < 4; ch++) {
        int cbase = ch * 32;
        float h[32];
        #pragma unroll
        for (int i = 0; i < 8; i++) {
            float4 u = ew[ch*8 + i];
            h[4*i+0] = u.x; h[4*i+1] = u.y; h[4*i+2] = u.z; h[4*i+3] = u.w;
        }
        g1_accum32(nf4, 7, W0, cbase, h);
        g1_tail3(v7.x, v7.y, v7.z, W0 + 28*128, cbase, h);
        #pragma unroll
        for (int i = 0; i < 32; i++) h[i] = fmaxf(h[i], 0.0f);
        g2_accum64(sb, h, W1 + 64, cbase, 128, o);
    }
    if (valid) {
        float4* out4 = reinterpret_cast<float4*>(nodeT + (size_t)n * 64);
        #pragma unroll
        for (int i = 0; i < 16; i++)
            out4[i] = make_float4(o[4*i], o[4*i+1], o[4*i+2], o[4*i+3]);
    }
}

// ---------------- tiled edge encoder ----------------------------------------

__global__ __launch_bounds__(256, 3) void k_enc_edge_T(
    const float* __restrict__ edgeF, const int* __restrict__ perm, int usePerm,
    const float* __restrict__ W0, const float* __restrict__ b0,
    const float* __restrict__ W1, const float* __restrict__ b1,
    float* __restrict__ edgeT, int E) {
    __shared__ float H[128 * 68];     // H[c][e], stride 68
    __shared__ float Wbuf[32 * 68];   // W1 chunk
    __shared__ float Xs[64 * 4];

    int t = threadIdx.x;
    int base = blockIdx.x * 64;

    if (t < 192) {
        int i = t / 3, j = t - i * 3;
        int e = base + i; int ec = (e < E) ? e : E - 1;
        int e2 = usePerm ? perm[ec] : ec;
        Xs[i * 4 + j] = edgeF[(size_t)e2 * 3 + j];
    }
    __syncthreads();

    int eg = t & 15, cg = t >> 4;
    float c1[4][8];
    {
        float4 b0a = *reinterpret_cast<const float4*>(b0 + cg * 8);
        float4 b0b = *reinterpret_cast<const float4*>(b0 + cg * 8 + 4);
        float bb[8] = {b0a.x,b0a.y,b0a.z,b0a.w,b0b.x,b0b.y,b0b.z,b0b.w};
        #pragma unroll
        for (int ie = 0; ie < 4; ie++)
            #pragma unroll
            for (int jc = 0; jc < 8; jc++) c1[ie][jc] = bb[jc];
    }
    #pragma unroll
    for (int k = 0; k < 3; k++) {
        float4 wa = *reinterpret_cast<const float4*>(W0 + k * 128 + cg * 8);
        float4 wb = *reinterpret_cast<const float4*>(W0 + k * 128 + cg * 8 + 4);
        float ww[8] = {wa.x,wa.y,wa.z,wa.w,wb.x,wb.y,wb.z,wb.w};
        #pragma unroll
        for (int ie = 0; ie < 4; ie++) {
            float a = Xs[(eg + 16 * ie) * 4 + k];
            #pragma unroll
            for (int jc = 0; jc < 8; jc++)
                c1[ie][jc] = fmaf(a, ww[jc], c1[ie][jc]);
        }
    }

    // prefetch W1 phase 0 slice into regs
    int wr_r = t >> 3, wr_cb = t & 7;
    float4 wreg2[2];
    {
        const float4* wr = reinterpret_cast<const float4*>(
            W1 + (size_t)(wr_r) * 128 + 64 + wr_cb * 8);
        wreg2[0] = wr[0]; wreg2[1] = wr[1];
    }

    #pragma unroll
    for (int ie = 0; ie < 4; ie++)
        #pragma unroll
        for (int jc = 0; jc < 8; jc++)
            H[(cg * 8 + jc) * 68 + eg + 16 * ie] = fmaxf(c1[ie][jc], 0.0f);

    int eg2 = t & 15, cg2 = t >> 4;
    float c2[4][4];
    {
        float4 bv = *reinterpret_cast<const float4*>(b1 + 64 + cg2 * 4);
        #pragma unroll
        for (int ie = 0; ie < 4; ie++) {
            c2[ie][0]=bv.x; c2[ie][1]=bv.y; c2[ie][2]=bv.z; c2[ie][3]=bv.w;
        }
    }
    #pragma clang loop unroll(disable)
    for (int phase = 0; phase < 4; phase++) {
        __syncthreads();                  // H written / prev Wbuf reads done
        {
            float* wd = Wbuf + wr_r * 68 + wr_cb * 8;
            wd[0]=wreg2[0].x; wd[1]=wreg2[0].y; wd[2]=wreg2[0].z; wd[3]=wreg2[0].w;
            wd[4]=wreg2[1].x; wd[5]=wreg2[1].y; wd[6]=wreg2[1].z; wd[7]=wreg2[1].w;
        }
        __syncthreads();
        if (phase < 3) {
            const float4* wr = reinterpret_cast<const float4*>(
                W1 + (size_t)((phase + 1) * 32 + wr_r) * 128 + 64 + wr_cb * 8);
            wreg2[0] = wr[0]; wreg2[1] = wr[1];
        }
        #pragma clang loop unroll_count(4)
        for (int k = 0; k < 32; k++) {
            int c = phase * 32 + k;
            float4 av = *reinterpret_cast<const float4*>(H + c * 68 + eg2 * 4);
            float4 b4 = *reinterpret_cast<const float4*>(Wbuf + k * 68 + cg2 * 4);
            G2_FMA16(av, b4, c2)
        }
    }
    #pragma unroll
    for (int ie = 0; ie < 4; ie++) {
        int e = base + eg2 * 4 + ie;
        if (e < E) {
            *reinterpret_cast<float4*>(edgeT + (size_t)e * 64 + cg2 * 4) =
                make_float4(c2[ie][0], c2[ie][1], c2[ie][2], c2[ie][3]);
        }
    }
}

// ------------- tiled per-step node projection --------------------------------
// Pd[64n x 128c] = b0 + nodeT[64n x 64] @ W0[64:128][0:128]

__global__ __launch_bounds__(256, 4) void k_node_pre_T(
    const float* __restrict__ nodeT, const float* __restrict__ W0,
    const float* __restrict__ b0, float* __restrict__ Pd, int N) {
    __shared__ float As[64 * 68];     // A[n][k], stride 68
    __shared__ float Wbuf[32 * 132];

    int t = threadIdx.x;
    int base = blockIdx.x * 64;

    {
        int i = t >> 2, q = t & 3;
        int n = base + i; int nc = (n < N) ? n : N - 1;
        const float4* tr = reinterpret_cast<const float4*>(nodeT + (size_t)nc * 64 + q * 16);
        float4* ad = reinterpret_cast<float4*>(As + i * 68 + q * 16);
        ad[0]=tr[0]; ad[1]=tr[1]; ad[2]=tr[2]; ad[3]=tr[3];
    }

    int ng = t & 15, cg = t >> 4;
    float c[4][8];
    {
        float4 b0a = *reinterpret_cast<const float4*>(b0 + cg * 8);
        float4 b0b = *reinterpret_cast<const float4*>(b0 + cg * 8 + 4);
        float bb[8] = {b0a.x,b0a.y,b0a.z,b0a.w,b0b.x,b0b.y,b0b.z,b0b.w};
        #pragma unroll
        for (int in = 0; in < 4; in++)
            #pragma unroll
            for (int jc = 0; jc < 8; jc++) c[in][jc] = bb[jc];
    }

    int wr_r = t >> 3, wr_cb = t & 7;
    #pragma clang loop unroll(disable)
    for (int phase = 0; phase < 2; phase++) {
        __syncthreads();
        {
            const float4* wr = reinterpret_cast<const float4*>(
                W0 + (size_t)(64 + phase * 32 + wr_r) * 128 + wr_cb * 16);
            float4* wd = reinterpret_cast<float4*>(Wbuf + wr_r * 132 + wr_cb * 16);
            wd[0]=wr[0]; wd[1]=wr[1]; wd[2]=wr[2]; wd[3]=wr[3];
        }
        __syncthreads();
        int koff = phase * 32;
        #pragma clang loop unroll_count(4)
        for (int k = 0; k < 32; k++) {
            float a0 = As[(ng + 16*0)*68 + koff + k];
            float a1 = As[(ng + 16*1)*68 + koff + k];
            float a2 = As[(ng + 16*2)*68 + koff + k];
            float a3 = As[(ng + 16*3)*68 + koff + k];
            const float* wrp = Wbuf + k * 132 + cg * 8;
            float4 bq0 = *reinterpret_cast<const float4*>(wrp);
            float4 bq1 = *reinterpret_cast<const float4*>(wrp + 4);
            float bb[8] = {bq0.x,bq0.y,bq0.z,bq0.w,bq1.x,bq1.y,bq1.z,bq1.w};
            #pragma unroll
            for (int jc = 0; jc < 8; jc++) {
                c[0][jc] = fmaf(a0, bb[jc], c[0][jc]);
                c[1][jc] = fmaf(a1, bb[jc], c[1][jc]);
                c[2][jc] = fmaf(a2, bb[jc], c[2][jc]);
                c[3][jc] = fmaf(a3, bb[jc], c[3][jc]);
            }
        }
    }

    #pragma unroll
    for (int in = 0; in < 4; in++) {
        int n = base + ng + 16 * in;
        if (n < N) {
            float4* o4 = reinterpret_cast<float4*>(Pd + (size_t)n * 128 + cg * 8);
            o4[0] = make_float4(c[in][0], c[in][1], c[in][2], c[in][3]);
            o4[1] = make_float4(c[in][4], c[in][5], c[in][6], c[in][7]);
        }
    }
}

// ------------- tiled edge core (R12: de-spilled GEMM2) ----------------------

__global__ __launch_bounds__(256, 3) void k_edge_core_T(
    float* __restrict__ edgeT, const float* __restrict__ Pd,
    const float* __restrict__ nodeT,
    const int* __restrict__ srcI, const int* __restrict__ dstI,
    const float* __restrict__ W0, const float* __restrict__ W1,
    const float* __restrict__ b1, int E) {
    __shared__ float Abuf[2 * 64 * 68];   // A_e | A_s (stride 68); later H[128][68]
    __shared__ float Wbuf[32 * 132];

    int t = threadIdx.x;
    int base = blockIdx.x * 64;

    // ---- stage A_e (edgeT rows) and A_s (nodeT[src] rows), float4 ----
    {
        int i = t >> 2, q = t & 3;
        int e = base + i; int ec = (e < E) ? e : E - 1;
        const float4* er = reinterpret_cast<const float4*>(edgeT + (size_t)ec * 64 + q * 16);
        int s = srcI[ec];
        const float4* sr = reinterpret_cast<const float4*>(nodeT + (size_t)s * 64 + q * 16);
        float4* ae = reinterpret_cast<float4*>(Abuf + i * 68 + q * 16);
        float4* as = reinterpret_cast<float4*>(Abuf + 64 * 68 + i * 68 + q * 16);
        #pragma unroll
        for (int j4 = 0; j4 < 4; j4++) { ae[j4] = er[j4]; as[j4] = sr[j4]; }
    }

    // ---- init C1 from Pd[dst]; edges e = eg + 16*ie ----
    int eg = t & 15, cg = t >> 4;
    float c1[4][8];
    #pragma unroll
    for (int ie = 0; ie < 4; ie++) {
        int e = base + eg + 16 * ie; int ec = (e < E) ? e : E - 1;
        int d = dstI[ec];
        const float4* pr = reinterpret_cast<const float4*>(Pd + (size_t)d * 128 + cg * 8);
        float4 p0 = pr[0], p1 = pr[1];
        c1[ie][0]=p0.x; c1[ie][1]=p0.y; c1[ie][2]=p0.z; c1[ie][3]=p0.w;
        c1[ie][4]=p1.x; c1[ie][5]=p1.y; c1[ie][6]=p1.z; c1[ie][7]=p1.w;
    }

    // ---- GEMM1: 4 phases, W rows {0,32,128,160}, reg-prefetched ----
    int wr_r = t >> 3, wr_cb = t & 7;
    float4 wreg[4];
    {
        const float4* wr = reinterpret_cast<const float4*>(
            W0 + (size_t)wr_r * 128 + wr_cb * 16);
        wreg[0]=wr[0]; wreg[1]=wr[1]; wreg[2]=wr[2]; wreg[3]=wr[3];
    }
    #pragma clang loop unroll(disable)
    for (int phase = 0; phase < 4; phase++) {
        const float* Asrc = Abuf + ((phase < 2) ? 0 : 64 * 68);
        int koff = (phase & 1) * 32;
        __syncthreads();                  // A staged (p0) / prev Wbuf reads done
        {
            float4* wd = reinterpret_cast<float4*>(Wbuf + wr_r * 132 + wr_cb * 16);
            wd[0]=wreg[0]; wd[1]=wreg[1]; wd[2]=wreg[2]; wd[3]=wreg[3];
        }
        __syncthreads();
        if (phase < 3) {
            int wrow_n = (phase + 1 < 2) ? (phase + 1) * 32 : 128 + (phase - 1) * 32;
            const float4* wr = reinterpret_cast<const float4*>(
                W0 + (size_t)(wrow_n + wr_r) * 128 + wr_cb * 16);
            wreg[0]=wr[0]; wreg[1]=wr[1]; wreg[2]=wr[2]; wreg[3]=wr[3];
        }
        #pragma clang loop unroll_count(4)
        for (int k = 0; k < 32; k++) {
            float a0 = Asrc[(eg + 16*0)*68 + koff + k];
            float a1 = Asrc[(eg + 16*1)*68 + koff + k];
            float a2 = Asrc[(eg + 16*2)*68 + koff + k];
            float a3 = Asrc[(eg + 16*3)*68 + koff + k];
            const float* wrp = Wbuf + k * 132 + cg * 8;
            float4 bq0 = *reinterpret_cast<const float4*>(wrp);
            float4 bq1 = *reinterpret_cast<const float4*>(wrp + 4);
            float bb[8] = {bq0.x,bq0.y,bq0.z,bq0.w,bq1.x,bq1.y,bq1.z,bq1.w};
            #pragma unroll
            for (int jc = 0; jc < 8; jc++) {
                c1[0][jc] = fmaf(a0, bb[jc], c1[0][jc]);
                c1[1][jc] = fmaf(a1, bb[jc], c1[1][jc]);
                c1[2][jc] = fmaf(a2, bb[jc], c1[2][jc]);
                c1[3][jc] = fmaf(a3, bb[jc], c1[3][jc]);
            }
        }
    }

    // prefetch W1 phase-0 slice (overlaps H write + barrier)
    float4 wreg2[2];
    {
        const float4* wr = reinterpret_cast<const float4*>(
            W1 + (size_t)(wr_r) * 64 + wr_cb * 8);
        wreg2[0] = wr[0]; wreg2[1] = wr[1];
    }

    __syncthreads();                      // all A reads done -> alias as H
    float* H = Abuf;                      // H[c][e], stride 68
    #pragma unroll
    for (int ie = 0; ie < 4; ie++)
        #pragma unroll
        for (int jc = 0; jc < 8; jc++)
            H[(cg*8 + jc) * 68 + eg + 16*ie] = fmaxf(c1[ie][jc], 0.0f);

    // ---- GEMM2: 4 phases, b128 H-reads, de-spilled inner ----
    int eg2 = t & 15, cg2 = t >> 4;
    float c2[4][4];
    {
        float4 bv = *reinterpret_cast<const float4*>(b1 + cg2 * 4);
        #pragma unroll
        for (int ie = 0; ie < 4; ie++) {
            c2[ie][0]=bv.x; c2[ie][1]=bv.y; c2[ie][2]=bv.z; c2[ie][3]=bv.w;
        }
    }
    #pragma clang loop unroll(disable)
    for (int phase = 0; phase < 4; phase++) {
        __syncthreads();                  // H written (p0) / prev Wbuf reads done
        {
            float* wd = Wbuf + wr_r * 68 + wr_cb * 8;
            wd[0]=wreg2[0].x; wd[1]=wreg2[0].y; wd[2]=wreg2[0].z; wd[3]=wreg2[0].w;
            wd[4]=wreg2[1].x; wd[5]=wreg2[1].y; wd[6]=wreg2[1].z; wd[7]=wreg2[1].w;
        }
        __syncthreads();
        if (phase < 3) {
            const float4* wr = reinterpret_cast<const float4*>(
                W1 + (size_t)((phase + 1) * 32 + wr_r) * 64 + wr_cb * 8);
            wreg2[0] = wr[0]; wreg2[1] = wr[1];
        }
        #pragma clang loop unroll_count(4)
        for (int k = 0; k < 32; k++) {
            int c = phase * 32 + k;
            float4 av = *reinterpret_cast<const float4*>(H + c * 68 + eg2 * 4);
            float4 b4 = *reinterpret_cast<const float4*>(Wbuf + k * 68 + cg2 * 4);
            G2_FMA16(av, b4, c2)
        }
    }

    #pragma unroll
    for (int ie = 0; ie < 4; ie++) {
        int e = base + eg2 * 4 + ie;
        if (e < E) {
            float4* er = reinterpret_cast<float4*>(edgeT + (size_t)e * 64 + cg2 * 4);
            float4 old = *er;
            old.x += c2[ie][0]; old.y += c2[ie][1];
            old.z += c2[ie][2]; old.w += c2[ie][3];
            *er = old;
        }
    }
}

// ------------- tiled node core (R12: de-spilled GEMM2) ----------------------

__global__ __launch_bounds__(256, 3) void k_node_core_T(
    const float* __restrict__ aggT, float* __restrict__ nodeT,
    const float* __restrict__ W0, const float* __restrict__ b0,
    const float* __restrict__ W1, const float* __restrict__ b1, int N) {
    __shared__ float Abuf[64 * 136];      // A[n][k] stride 132; H[128][68] = 8704
    __shared__ float Wbuf[32 * 132];

    int t = threadIdx.x;
    int base = blockIdx.x * 64;

    {
        int i = t >> 2, q = t & 3;
        int n = base + i; int nc = (n < N) ? n : N - 1;
        const float4* gr = reinterpret_cast<const float4*>(aggT + (size_t)nc * 64 + q * 16);
        const float4* tr = reinterpret_cast<const float4*>(nodeT + (size_t)nc * 64 + q * 16);
        float4* ag = reinterpret_cast<float4*>(Abuf + i * 132 + q * 16);
        float4* at = reinterpret_cast<float4*>(Abuf + i * 132 + 64 + q * 16);
        #pragma unroll
        for (int j4 = 0; j4 < 4; j4++) { ag[j4] = gr[j4]; at[j4] = tr[j4]; }
    }

    int ng = t & 15, cg = t >> 4;
    float c1[4][8];
    {
        float4 b0a = *reinterpret_cast<const float4*>(b0 + cg * 8);
        float4 b0b = *reinterpret_cast<const float4*>(b0 + cg * 8 + 4);
        float bb[8] = {b0a.x,b0a.y,b0a.z,b0a.w,b0b.x,b0b.y,b0b.z,b0b.w};
        #pragma unroll
        for (int in = 0; in < 4; in++)
            #pragma unroll
            for (int jc = 0; jc < 8; jc++) c1[in][jc] = bb[jc];
    }

    int wr_r = t >> 3, wr_cb = t & 7;
    float4 wreg[4];
    {
        const float4* wr = reinterpret_cast<const float4*>(
            W0 + (size_t)wr_r * 128 + wr_cb * 16);
        wreg[0]=wr[0]; wreg[1]=wr[1]; wreg[2]=wr[2]; wreg[3]=wr[3];
    }
    #pragma clang loop unroll(disable)
    for (int phase = 0; phase < 4; phase++) {
        int koff = phase * 32;
        __syncthreads();
        {
            float4* wd = reinterpret_cast<float4*>(Wbuf + wr_r * 132 + wr_cb * 16);
            wd[0]=wreg[0]; wd[1]=wreg[1]; wd[2]=wreg[2]; wd[3]=wreg[3];
        }
        __syncthreads();
        if (phase < 3) {
            const float4* wr = reinterpret_cast<const float4*>(
                W0 + (size_t)((phase + 1) * 32 + wr_r) * 128 + wr_cb * 16);
            wreg[0]=wr[0]; wreg[1]=wr[1]; wreg[2]=wr[2]; wreg[3]=wr[3];
        }
        #pragma clang loop unroll_count(4)
        for (int k = 0; k < 32; k++) {
            float a0 = Abuf[(ng + 16*0)*132 + koff + k];
            float a1 = Abuf[(ng + 16*1)*132 + koff + k];
            float a2 = Abuf[(ng + 16*2)*132 + koff + k];
            float a3 = Abuf[(ng + 16*3)*132 + koff + k];
            const float* wrp = Wbuf + k * 132 + cg * 8;
            float4 bq0 = *reinterpret_cast<const float4*>(wrp);
            float4 bq1 = *reinterpret_cast<const float4*>(wrp + 4);
            float bb[8] = {bq0.x,bq0.y,bq0.z,bq0.w,bq1.x,bq1.y,bq1.z,bq1.w};
            #pragma unroll
            for (int jc = 0; jc < 8; jc++) {
                c1[0][jc] = fmaf(a0, bb[jc], c1[0][jc]);
                c1[1][jc] = fmaf(a1, bb[jc], c1[1][jc]);
                c1[2][jc] = fmaf(a2, bb[jc], c1[2][jc]);
                c1[3][jc] = fmaf(a3, bb[jc], c1[3][jc]);
            }
        }
    }

    float4 wreg2[2];
    {
        const float4* wr = reinterpret_cast<const float4*>(
            W1 + (size_t)wr_r * 64 + wr_cb * 8);
        wreg2[0] = wr[0]; wreg2[1] = wr[1];
    }

    __syncthreads();
    float* H = Abuf;                      // H[c][n], stride 68
    #pragma unroll
    for (int in = 0; in < 4; in++)
        #pragma unroll
        for (int jc = 0; jc < 8; jc++)
            H[(cg*8 + jc) * 68 + ng + 16*in] = fmaxf(c1[in][jc], 0.0f);

    int ng2 = t & 15, cg2 = t >> 4;
    float c2[4][4];
    {
        float4 bv = *reinterpret_cast<const float4*>(b1 + cg2 * 4);
        #pragma unroll
        for (int in = 0; in < 4; in++) {
            c2[in][0]=bv.x; c2[in][1]=bv.y; c2[in][2]=bv.z; c2[in][3]=bv.w;
        }
    }
    #pragma clang loop unroll(disable)
    for (int phase = 0; phase < 4; phase++) {
        __syncthreads();
        {
            float* wd = Wbuf + wr_r * 68 + wr_cb * 8;
            wd[0]=wreg2[0].x; wd[1]=wreg2[0].y; wd[2]=wreg2[0].z; wd[3]=wreg2[0].w;
            wd[4]=wreg2[1].x; wd[5]=wreg2[1].y; wd[6]=wreg2[1].z; wd[7]=wreg2[1].w;
        }
        __syncthreads();
        if (phase < 3) {
            const float4* wr = reinterpret_cast<const float4*>(
                W1 + (size_t)((phase + 1) * 32 + wr_r) * 64 + wr_cb * 8);
            wreg2[0] = wr[0]; wreg2[1] = wr[1];
        }
        #pragma clang loop unroll_count(4)
        for (int k = 0; k < 32; k++) {
            int c = phase * 32 + k;
            float4 av = *reinterpret_cast<const float4*>(H + c * 68 + ng2 * 4);
            float4 b4 = *reinterpret_cast<const float4*>(Wbuf + k * 68 + cg2 * 4);
            G2_FMA16(av, b4, c2)
        }
    }

    #pragma unroll
    for (int in = 0; in < 4; in++) {
        int n = base + ng2 * 4 + in;
        if (n < N) {
            float4* nr = reinterpret_cast<float4*>(nodeT + (size_t)n * 64 + cg2 * 4);
            float4 old = *nr;
            old.x += c2[in][0]; old.y += c2[in][1];
            old.z += c2[in][2]; old.w += c2[in][3];
            *nr = old;
        }
    }
}

// ------------- plan B edge core (all inline, original order) ----------------

__global__ __launch_bounds__(256, 2) void k_edge_core_B(
    float* __restrict__ edgeT, const float* __restrict__ nodeT,
    const int* __restrict__ src, const int* __restrict__ dst,
    const float* __restrict__ W0, const float* __restrict__ b0,
    const float* __restrict__ W1, const float* __restrict__ b1, int E) {
    __shared__ float sb[32 * 256];
    int e = blockIdx.x * 256 + threadIdx.x;
    bool valid = e < E;
    int ec = valid ? e : E - 1;
    int d = dst[ec], s = src[ec];
    const float4* a4 = reinterpret_cast<const float4*>(edgeT + (size_t)ec * 64);
    const float4* d4 = reinterpret_cast<const float4*>(nodeT + (size_t)d * 64);
    const float4* s4 = reinterpret_cast<const float4*>(nodeT + (size_t)s * 64);

    float o[64];
    const float4* bv = reinterpret_cast<const float4*>(b1);
    #pragma unroll
    for (int i = 0; i < 16; i++) {
        float4 b = bv[i];
        o[4*i+0] = b.x; o[4*i+1] = b.y; o[4*i+2] = b.z; o[4*i+3] = b.w;
    }
    #pragma unroll
    for (int ch = 0; ch < 4; ch++) {
        int cbase = ch * 32;
        float h[32];
        const float4* b0v = reinterpret_cast<const float4*>(b0 + cbase);
        #pragma unroll
        for (int i = 0; i < 8; i++) {
            float4 b = b0v[i];
            h[4*i+0] = b.x; h[4*i+1] = b.y; h[4*i+2] = b.z; h[4*i+3] = b.w;
        }
        g1_accum32(a4, 16, W0, cbase, h);
        g1_accum32(d4, 16, W0 + 64*128, cbase, h);
        g1_accum32(s4, 16, W0 + 128*128, cbase, h);
        #pragma unroll
        for (int i = 0; i < 32; i++) h[i] = fmaxf(h[i], 0.0f);
        g2_accum64(sb, h, W1, cbase, 64, o);
    }
    if (valid) {
        float4* eo4 = reinterpret_cast<float4*>(edgeT + (size_t)e * 64);
        #pragma unroll
        for (int i = 0; i < 16; i++) {
            float4 t = a4[i];
            t.x += o[4*i+0]; t.y += o[4*i+1];
            t.z += o[4*i+2]; t.w += o[4*i+3];
            eo4[i] = t;
        }
    }
}

// ------------- mean aggregation (fp64, order-invariant) ---------------------

__global__ __launch_bounds__(256) void k_agg_csr(
    const float* __restrict__ edgeT, const int* __restrict__ row_off,
    const float* __restrict__ inv_cnt, float* __restrict__ aggT, int N) {
    int n = blockIdx.x * 4 + (threadIdx.x >> 6);
    int lane = threadIdx.x & 63;
    if (n >= N) return;
    int beg = row_off[n], end = row_off[n + 1];
    double s = 0.0;
    for (int idx = beg; idx < end; idx++)
        s += (double)edgeT[(size_t)idx * 64 + lane];
    aggT[(size_t)n * 64 + lane] = (float)(s * (double)inv_cnt[n]);
}

__global__ __launch_bounds__(256) void k_agg_gather(
    const float* __restrict__ edgeT, const int* __restrict__ row_off,
    const int* __restrict__ edge_list, const float* __restrict__ inv_cnt,
    float* __restrict__ aggT, int N) {
    int n = blockIdx.x * 4 + (threadIdx.x >> 6);
    int lane = threadIdx.x & 63;
    if (n >= N) return;
    int beg = row_off[n], end = row_off[n + 1];
    double s = 0.0;
    for (int idx = beg; idx < end; idx++) {
        int e = edge_list[idx];
        s += (double)edgeT[(size_t)e * 64 + lane];
    }
    aggT[(size_t)n * 64 + lane] = (float)(s * (double)inv_cnt[n]);
}

// ------------- decoder — R5 version -----------------------------------------

__global__ __launch_bounds__(256, 2) void k_decode(
    const float* __restrict__ nodeF, const float* __restrict__ embW,
    const float* __restrict__ encW0, const float* __restrict__ encW1,
    const float* __restrict__ encb1, const float* __restrict__ nodeT,
    const float* __restrict__ W0, const float* __restrict__ b0,
    const float* __restrict__ W1, const float* __restrict__ b1,
    float* __restrict__ out, int N) {
    __shared__ float sb[64 * 256];
    int t = threadIdx.x;
    int n = blockIdx.x * 256 + t;
    bool valid = n < N;
    int nc = valid ? n : N - 1;
    const float4* nf4 = reinterpret_cast<const float4*>(nodeF + (size_t)nc * 32);
    const float4* t4  = reinterpret_cast<const float4*>(nodeT + (size_t)nc * 64);
    float4 v7 = nf4[7];
    int p = (int)(v7.w + 0.5f);
    const float4* ew = reinterpret_cast<const float4*>(embW + p * 128);

    float head[64];
    const float4* ebv = reinterpret_cast<const float4*>(encb1);
    #pragma unroll
    for (int i = 0; i < 16; i++) {
        float4 b = ebv[i];
        head[4*i+0] = b.x; head[4*i+1] = b.y; head[4*i+2] = b.z; head[4*i+3] = b.w;
    }
    #pragma unroll
    for (int ch = 0; ch < 4; ch++) {
        int cbase = ch * 32;
        float h[32];
        #pragma unroll
        for (int i = 0; i < 8; i++) {
            float4 u = ew[ch*8 + i];
            h[4*i+0] = u.x; h[4*i+1] = u.y; h[4*i+2] = u.z; h[4*i+3] = u.w;
        }
        g1_accum32(nf4, 7, encW0, cbase, h);
        g1_tail3(v7.x, v7.y, v7.z, encW0 + 28*128, cbase, h);
        #pragma unroll
        for (int i = 0; i < 32; i++) h[i] = fmaxf(h[i], 0.0f);
        g2_accum64(sb, h, encW1, cbase, 128, head);
    }

    #pragma unroll
    for (int k = 0; k < 64; k++) sb[k * 256 + t] = head[k];
    __syncthreads();

    float h2[128];
    #pragma unroll
    for (int ch = 0; ch < 4; ch++) {
        int cbase = ch * 32;
        float* hc = &h2[ch * 32];
        const float4* b0v = reinterpret_cast<const float4*>(b0 + cbase);
        #pragma unroll
        for (int i = 0; i < 8; i++) {
            float4 b = b0v[i];
            hc[4*i+0] = b.x; hc[4*i+1] = b.y; hc[4*i+2] = b.z; hc[4*i+3] = b.w;
        }
        #pragma clang loop unroll(disable)
        for (int k = 0; k < 64; k++) {
            float hk = sb[k * 256 + t];
            const float4* w = reinterpret_cast<const float4*>(W0 + (size_t)k * 128 + cbase);
            #pragma unroll
            for (int cg = 0; cg < 8; cg++) {
                float4 wv = w[cg];
                hc[cg*4+0] = fmaf(hk, wv.x, hc[cg*4+0]);
                hc[cg*4+1] = fmaf(hk, wv.y, hc[cg*4+1]);
                hc[cg*4+2] = fmaf(hk, wv.z, hc[cg*4+2]);
                hc[cg*4+3] = fmaf(hk, wv.w, hc[cg*4+3]);
            }
        }
        g1_accum32(t4, 16, W0 + 64*128, cbase, hc);
    }
    __syncthreads();

    float o0 = b1[0], o1 = b1[1], o2 = b1[2];
    #pragma unroll
    for (int ch = 0; ch < 4; ch++) {
        int kb = ch * 32;
        #pragma unroll
        for (int k = 0; k < 32; k++) sb[k * 256 + t] = fmaxf(h2[kb + k], 0.0f);
        __syncthreads();
        #pragma clang loop unroll(disable)
        for (int k = 0; k < 32; k++) {
            float hk = sb[k * 256 + t];
            const float* w = W1 + (size_t)(kb + k) * 3;
            o0 = fmaf(hk, w[0], o0);
            o1 = fmaf(hk, w[1], o1);
            o2 = fmaf(hk, w[2], o2);
        }
        __syncthreads();
    }
    if (valid) {
        out[(size_t)n * 3 + 0] = o0;
        out[(size_t)n * 3 + 1] = o1;
        out[(size_t)n * 3 + 2] = o2;
    }
}

// ---------------------------------------------------------------------------

extern "C" void kernel_launch(void* const* d_in, const int* in_sizes, int n_in,
                              void* d_out, int out_size, void* d_ws, size_t ws_size,
                              hipStream_t stream) {
    const int*   edge_index = (const int*)  d_in[0];
    const float* nodeF      = (const float*)d_in[1];
    const float* edgeF      = (const float*)d_in[2];
    const float* emb        = (const float*)d_in[3];
    const float* enc_n_W0   = (const float*)d_in[4];
    const float* enc_n_b0   = (const float*)d_in[5];
    const float* enc_n_W1   = (const float*)d_in[6];
    const float* enc_n_b1   = (const float*)d_in[7];
    const float* enc_e_W0   = (const float*)d_in[8];
    const float* enc_e_b0   = (const float*)d_in[9];
    const float* enc_e_W1   = (const float*)d_in[10];
    const float* enc_e_b1   = (const float*)d_in[11];
    const float* core_e_W0  = (const float*)d_in[12];
    const float* core_e_b0  = (const float*)d_in[13];
    const float* core_e_W1  = (const float*)d_in[14];
    const float* core_e_b1  = (const float*)d_in[15];
    const float* core_n_W0  = (const float*)d_in[16];
    const float* core_n_b0  = (const float*)d_in[17];
    const float* core_n_W1  = (const float*)d_in[18];
    const float* core_n_b1  = (const float*)d_in[19];
    const float* dec_W0     = (const float*)d_in[20];
    const float* dec_b0     = (const float*)d_in[21];
    const float* dec_W1     = (const float*)d_in[22];
    const float* dec_b1     = (const float*)d_in[23];
    (void)n_in; (void)out_size;

    const int E = in_sizes[0] / 2;
    const int N = in_sizes[1] / 32;
    const int* src = edge_index;
    const int* dst = edge_index + E;

    auto al = [](size_t x) { return (x + 255) & ~(size_t)255; };
    const size_t szEdgeT = al((size_t)E * 64 * 4);
    const size_t szNodeT = al((size_t)N * 64 * 4);
    const size_t szP     = al((size_t)N * 128 * 4);
    const size_t szAgg   = al((size_t)N * 64 * 4);
    const size_t szElist = al((size_t)E * 4);
    const size_t szN4    = al((size_t)N * 4);
    const size_t szRow   = al((size_t)(N + 1) * 4);
    const size_t szEmbW  = al(2 * 128 * 4);
    const size_t base = szEdgeT + szNodeT + szElist + szRow + 3 * szN4 + szEmbW;
    const size_t needCSR = base + 2 * szElist + szP;
    const size_t needAp  = base + szP;
    const int plan = (ws_size >= needCSR) ? 0 : (ws_size >= needAp) ? 1 : 2;

    char* ws = (char*)d_ws;
    size_t off = 0;
    auto carve = [&](size_t bytes) -> char* { char* p = ws + off; off += bytes; return p; };
    float* edgeT   = (float*)carve(szEdgeT);
    float* nodeT   = (float*)carve(szNodeT);
    int*   elist   = (int*)  carve(szElist);
    int*   row_off = (int*)  carve(szRow);
    int*   counts  = (int*)  carve(szN4);
    int*   cursor  = (int*)  carve(szN4);
    float* inv_cnt = (float*)carve(szN4);
    float* embW    = (float*)carve(szEmbW);
    int *src_p = nullptr, *dst_p = nullptr;
    float *Pd = nullptr, *aggT = nullptr;
    if (plan == 0) {
        src_p = (int*)carve(szElist);
        dst_p = (int*)carve(szElist);
        Pd = (float*)carve(szP); aggT = Pd;   // lifetime-disjoint alias
    } else if (plan == 1) {
        Pd = (float*)carve(szP); aggT = Pd;
    } else {
        aggT = (float*)carve(szAgg);
    }

    int blkE = (E + 255) / 256;
    int blkN = (N + 255) / 256;
    int blkT = (E + 63) / 64;
    int blkNT = (N + 63) / 64;

    k_zero<<<(N + 255) / 256, 256, 0, stream>>>(counts, N);
    k_hist<<<blkE, 256, 0, stream>>>(dst, counts, E);
    k_scan<<<1, 1024, 0, stream>>>(counts, row_off, cursor, inv_cnt, N);
    k_fill<<<blkE, 256, 0, stream>>>(dst, cursor, elist, E);
    if (plan == 0)
        k_perm_idx<<<blkE, 256, 0, stream>>>(elist, src, dst, src_p, dst_p, E);

    k_embW<<<1, 128, 0, stream>>>(emb, enc_n_W0, enc_n_b0, embW);
    k_enc_node_tail<<<blkN, 256, 0, stream>>>(nodeF, embW, enc_n_W0, enc_n_W1,
                                              enc_n_b1, nodeT, N);
    k_enc_edge_T<<<blkT, 256, 0, stream>>>(edgeF, elist, (plan == 0) ? 1 : 0,
                                           enc_e_W0, enc_e_b0, enc_e_W1, enc_e_b1,
                                           edgeT, E);

    for (int step = 0; step < 3; step++) {
        if (plan == 0) {
            k_node_pre_T<<<blkNT, 256, 0, stream>>>(nodeT, core_e_W0, core_e_b0, Pd, N);
            k_edge_core_T<<<blkT, 256, 0, stream>>>(edgeT, Pd, nodeT, src_p, dst_p,
                                                    core_e_W0, core_e_W1, core_e_b1, E);
            k_agg_csr<<<(N + 3) / 4, 256, 0, stream>>>(edgeT, row_off, inv_cnt, aggT, N);
        } else if (plan == 1) {
            k_node_pre_T<<<blkNT, 256, 0, stream>>>(nodeT, core_e_W0, core_e_b0, Pd, N);
            k_edge_core_T<<<blkT, 256, 0, stream>>>(edgeT, Pd, nodeT, src, dst,
                                                    core_e_W0, core_e_W1, core_e_b1, E);
            k_agg_gather<<<(N + 3) / 4, 256, 0, stream>>>(edgeT, row_off, elist,
                                                          inv_cnt, aggT, N);
        } else {
            k_edge_core_B<<<blkE, 256, 0, stream>>>(edgeT, nodeT, src, dst,
                                                    core_e_W0, core_e_b0,
                                                    core_e_W1, core_e_b1, E);
            k_agg_gather<<<(N + 3) / 4, 256, 0, stream>>>(edgeT, row_off, elist,
                                                          inv_cnt, aggT, N);
        }
        k_node_core_T<<<blkNT, 256, 0, stream>>>(aggT, nodeT, core_n_W0, core_n_b0,
                                                 core_n_W1, core_n_b1, N);
    }
    k_decode<<<blkN, 256, 0, stream>>>(nodeF, embW, enc_n_W0, enc_n_W1, enc_n_b1,
                                       nodeT, dec_W0, dec_b0, dec_W1, dec_b1,
                                       (float*)d_out, N);
}